// Round 7
// baseline (329.492 us; speedup 1.0000x reference)
//
#include <hip/hip_runtime.h>
#include <hip/hip_bf16.h>

#define N_NODESC 50000
#define N_EDGESC 800000
#define DD 128
#define HH 8
#define HDIM 16
#define N_NT 3
#define N_ET 5
#define NPB 196    // node chunks (196*256 = 50176 >= 50000)
#define NEB 400    // edge-pass blocks in kernel A
#define NFB 512    // fill blocks in kernel C

// ---------------- workspace layout (bytes) ----------------
#define KV8_OFF    ((size_t)0)           // fp8 [N][256] bytes: K plane [0..127], V plane [128..255] (orig ids)
#define QT8_OFF    ((size_t)12800000)    // fp8 [N][640] 32 MB (orig ids, dead after tail)
#define XP_OFF     ((size_t)44800000)    // bf16 [N][128] permuted 12.8 MB (dead after proj)
#define WOUTT_OFF  ((size_t)83200000)    // bf16 [128][128] 32 KB
#define W1T_OFF    ((size_t)83232768)    // bf16 [512][128] 128 KB
#define W2T_OFF    ((size_t)83363840)    // bf16 [128][512] 128 KB
#define WALL_OFF   ((size_t)83494912)    // bf16 [3][896][128] 672 KB
#define EDATA_OFF  ((size_t)84183040)    // int [E] packed src|et<<16 (orig ids), 3.2 MB
#define ROWS_OFF   ((size_t)87383040)    // int [N+1] (+pad)
#define ORIG_OFF   ((size_t)87583104)    // int [N]
#define DEG_OFF    ((size_t)87783104)    // int [N] (memset 0)
#define TOFS_OFF   ((size_t)87983104)    // int [4]
#define BH_OFF     ((size_t)87983168)    // int [3*NPB]
#define BB_OFF     ((size_t)87985536)    // int [3*NPB]
#define TMP_OFF    ((size_t)87988928)    // uint [E] packed rank<<16|nd, 3.2 MB
#define RLOC_OFF   ((size_t)91188928)    // int [N+1] chunk-local exclusive deg scan
#define CSUM_OFF   ((size_t)91389056)    // int [NPB] per-chunk deg sums

using short8 = __attribute__((ext_vector_type(8))) short;
using f32x4  = __attribute__((ext_vector_type(4))) float;
using f32x2  = __attribute__((ext_vector_type(2))) float;

__device__ __forceinline__ ushort f2b(float f) {
    __hip_bfloat16 h = __float2bfloat16(f);
    return *(ushort*)&h;
}
__device__ __forceinline__ float b2f(ushort u) {
    __hip_bfloat16 h = *(__hip_bfloat16*)&u;
    return __bfloat162float(h);
}
__device__ __forceinline__ f32x2 pk0(unsigned int w) {
    return __builtin_amdgcn_cvt_pk_f32_fp8((int)w, false);   // bytes 0,1
}
__device__ __forceinline__ f32x2 pk1(unsigned int w) {
    return __builtin_amdgcn_cvt_pk_f32_fp8((int)w, true);    // bytes 2,3
}
// exact-form gelu with A&S 7.1.26 erf approx (|err_erf| < 1.6e-7, far below bf16 lsb)
__device__ __forceinline__ float gelu_f(float v) {
    const float x = v * 0.70710678118654752f;
    const float ax = fabsf(x);
    const float d = fmaf(0.3275911f, ax, 1.0f);
    float t;
    asm("v_rcp_f32 %0, %1" : "=v"(t) : "v"(d));
    float p = fmaf(1.061405429f, t, -1.453152027f);
    p = fmaf(p, t, 1.421413741f);
    p = fmaf(p, t, -0.284496736f);
    p = fmaf(p, t, 0.254829592f);
    p = p * t;
    const float e = __expf(-ax * ax);
    const float er = 1.0f - p * e;
    const float erfx = (x < 0.f) ? -er : er;
    return 0.5f * v * (1.0f + erfx);
}
// raw barrier: waits only LDS (lgkmcnt), NOT vmcnt -- in-flight global prefetch survives.
__device__ __forceinline__ void ebar() {
    __builtin_amdgcn_sched_barrier(0);
    asm volatile("s_waitcnt lgkmcnt(0)" ::: "memory");
    __builtin_amdgcn_sched_barrier(0);
    __builtin_amdgcn_s_barrier();
    __builtin_amdgcn_sched_barrier(0);
}

// ================= kernel A: wprep (b<1920) | phist (b<2116) | deg+rank (rest) =================
__global__ __launch_bounds__(256) void prep_a(
    const float* __restrict__ Wout, const float* __restrict__ W1, const float* __restrict__ W2,
    const float* __restrict__ WQ, const float* __restrict__ Wk, const float* __restrict__ Wv,
    const float* __restrict__ We, const float* __restrict__ mu,
    ushort* __restrict__ Woutt, ushort* __restrict__ W1t, ushort* __restrict__ W2t,
    ushort* __restrict__ Wall,
    const int* __restrict__ ntype, int* __restrict__ bh,
    const int* __restrict__ dst, int* __restrict__ deg, unsigned int* __restrict__ tmp)
{
    const int b = blockIdx.x, tid = threadIdx.x;
    if (b < 1920) {
        const int gid = b * 256 + tid;
        if (gid < 16384) {                       // Woutt[n][k] = Wout[k][n]
            const int nn = gid >> 7, k = gid & 127;
            Woutt[gid] = f2b(Wout[k * 128 + nn]);
        } else if (gid < 81920) {                // W1t[n][k] = W1[k][n]
            const int i = gid - 16384;
            const int nn = i >> 7, k = i & 127;
            W1t[i] = f2b(W1[k * 512 + nn]);
        } else if (gid < 147456) {               // W2t[n][k] = W2[k][n]
            const int i = gid - 81920;
            const int nn = i >> 9, k = i & 511;
            W2t[i] = f2b(W2[k * 128 + nn]);
        } else {                                 // Wall [4K | 4V | Qt et 0..4], block-diag per head
            const int idx = gid - 147456;        // < 344064
            const int t = idx / (896 * 128);
            const int rem = idx % (896 * 128);
            const int c = rem / 128, k = rem % 128;
            const int hk = k >> 4, ck = k & 15;
            float v = 0.f;
            if (c < 128) {
                const int hc = c >> 4, j = c & 15;
                if (hk == hc) v = 4.f * Wk[((t * HH + hc) * HDIM + ck) * HDIM + j];
            } else if (c < 256) {
                const int c2 = c - 128, hc = c2 >> 4, j = c2 & 15;
                if (hk == hc) v = 4.f * Wv[((t * HH + hc) * HDIM + ck) * HDIM + j];
            } else {
                const int cq = c - 256, et = cq >> 7, dd = cq & 127;
                const int hq = dd >> 4, j = dd & 15;
                if (hk == hq) {
                    const float* wq = WQ + ((t * HH + hq) * HDIM + ck) * HDIM;
                    const float* we = We + ((et * HH + hq) * HDIM + j) * HDIM;
                    float s = 0.f;
#pragma unroll
                    for (int f = 0; f < 16; f++) s = fmaf(wq[f], we[f], s);
                    v = 64.f * mu[hq * N_ET + et] * s;   // 64 = 256 fp8 scale * 0.25
                }
            }
            Wall[idx] = f2b(v);
        }
    } else if (b < 1920 + NPB) {
        const int bc = b - 1920;
        const int wave = tid >> 6, lane = tid & 63;
        const int n = bc * 256 + tid;
        const int t = (n < N_NODESC) ? ntype[n] : -1;
        const unsigned long long m0 = __ballot(t == 0);
        const unsigned long long m1 = __ballot(t == 1);
        const unsigned long long m2 = __ballot(t == 2);
        __shared__ int wcnt[4][3];
        if (lane == 0) {
            wcnt[wave][0] = (int)__popcll(m0);
            wcnt[wave][1] = (int)__popcll(m1);
            wcnt[wave][2] = (int)__popcll(m2);
        }
        __syncthreads();
        if (tid < 3)
            bh[tid * NPB + bc] = wcnt[0][tid] + wcnt[1][tid] + wcnt[2][tid] + wcnt[3][tid];
    } else {
        for (int e = (b - 1920 - NPB) * 256 + tid; e < N_EDGESC; e += NEB * 256) {
            const int nd = dst[e];
            const unsigned int p = (unsigned int)atomicAdd(&deg[nd], 1);
            tmp[e] = (p << 16) | (unsigned int)nd;
        }
    }
}

// ================= kernel B: permscan (block 0) | WIDE chunk-local deg scans (1..196) ============
__global__ __launch_bounds__(256) void prep_b(
    const int* __restrict__ bh, const int* __restrict__ deg,
    int* __restrict__ bb, int* __restrict__ tofs,
    int* __restrict__ rloc, int* __restrict__ csum)
{
    __shared__ int part[256];
    const int tid = threadIdx.x;
    if (blockIdx.x == 0) {
        // exclusive scan of 3*NPB=588 entries: 3 per thread
        const int base3 = tid * 3;
        int e0 = (base3 + 0 < 588) ? bh[base3 + 0] : 0;
        int e1 = (base3 + 1 < 588) ? bh[base3 + 1] : 0;
        int e2 = (base3 + 2 < 588) ? bh[base3 + 2] : 0;
        const int l0 = e0, l1 = e0 + e1, l2 = l1 + e2;
        part[tid] = l2;
        __syncthreads();
        for (int off = 1; off < 256; off <<= 1) {
            const int u = (tid >= off) ? part[tid - off] : 0;
            __syncthreads();
            part[tid] += u;
            __syncthreads();
        }
        const int tb = part[tid] - l2;
        if (base3 + 0 < 588) bb[base3 + 0] = tb;
        if (base3 + 1 < 588) bb[base3 + 1] = tb + l0;
        if (base3 + 2 < 588) bb[base3 + 2] = tb + l1;
        __syncthreads();
        if (tid == 0) {
            tofs[0] = 0;
            tofs[1] = bb[NPB];
            tofs[2] = bb[2 * NPB];
            tofs[3] = N_NODESC;
        }
    } else {
        // chunk-local exclusive scan (coalesced): chunk c covers nodes c*256..c*256+255
        const int c = blockIdx.x - 1;
        const int n = c * 256 + tid;
        const int vdeg = (n < N_NODESC) ? deg[n] : 0;
        part[tid] = vdeg;
        __syncthreads();
        for (int off = 1; off < 256; off <<= 1) {
            const int u = (tid >= off) ? part[tid - off] : 0;
            __syncthreads();
            part[tid] += u;
            __syncthreads();
        }
        if (n <= N_NODESC) rloc[n] = part[tid] - vdeg;   // includes rloc[N]
        if (tid == 255) csum[c] = part[255];
    }
}

// ================= kernel C: pscatter+Xp+rows (b<NPB) | fill edata (rest) =================
__global__ __launch_bounds__(256) void prep_c(
    const int* __restrict__ ntype, const float* __restrict__ x,
    const int* __restrict__ src, const int* __restrict__ etype,
    const int* __restrict__ bb, const int* __restrict__ rloc, const int* __restrict__ csum,
    const unsigned int* __restrict__ tmp,
    int* __restrict__ origof, ushort* __restrict__ Xp, int* __restrict__ rows,
    int* __restrict__ edata)
{
    const int b = blockIdx.x, tid = threadIdx.x;
    __shared__ int cb[256];   // exclusive chunk bases
    // every block: LDS scan of csum[196] -> exclusive bases (tiny, redundant, parallel)
    {
        const int v = (tid < NPB) ? csum[tid] : 0;
        cb[tid] = v;
        __syncthreads();
        for (int off = 1; off < 256; off <<= 1) {
            const int u = (tid >= off) ? cb[tid - off] : 0;
            __syncthreads();
            cb[tid] += u;
            __syncthreads();
        }
        const int incl = cb[tid];
        __syncthreads();
        cb[tid] = incl - v;   // exclusive
        __syncthreads();
    }

    if (b < NPB) {
        const int wave = tid >> 6, lane = tid & 63;
        const int n = b * 256 + tid;
        const int t = (n < N_NODESC) ? ntype[n] : -1;
        const unsigned long long m0 = __ballot(t == 0);
        const unsigned long long m1 = __ballot(t == 1);
        const unsigned long long m2 = __ballot(t == 2);
        __shared__ int wcnt[4][3];
        __shared__ int sp[256];
        if (lane == 0) {
            wcnt[wave][0] = (int)__popcll(m0);
            wcnt[wave][1] = (int)__popcll(m1);
            wcnt[wave][2] = (int)__popcll(m2);
        }
        __syncthreads();
        int p = -1;
        if (n < N_NODESC) {
            int basew = 0;
#pragma unroll
            for (int w = 0; w < 4; w++) if (w < wave) basew += wcnt[w][t];
            const unsigned long long mt = (t == 0) ? m0 : (t == 1) ? m1 : m2;
            const unsigned long long mlt = ((unsigned long long)1 << lane) - 1;
            p = bb[t * NPB + b] + basew + (int)__popcll(mt & mlt);
            origof[p] = n;
        }
        // final rows for this chunk (rloc[n] + chunk base); includes rows[N] from chunk 195
        if (n <= N_NODESC) rows[n] = cb[b] + rloc[n];
        sp[tid] = p;
        __syncthreads();
        // cooperative permuted bf16 copy: 256 nodes x 16 chunks of 8
        for (int i = tid; i < 256 * 16; i += 256) {
            const int nn = i >> 4, c = (i & 15) << 3;
            const int pp = sp[nn];
            if (pp < 0) continue;
            const int n2 = b * 256 + nn;
            const float4 v0 = *(const float4*)(x + (size_t)n2 * DD + c);
            const float4 v1 = *(const float4*)(x + (size_t)n2 * DD + c + 4);
            ushort o[8] = {f2b(v0.x), f2b(v0.y), f2b(v0.z), f2b(v0.w),
                           f2b(v1.x), f2b(v1.y), f2b(v1.z), f2b(v1.w)};
            *(uint4*)(Xp + (size_t)pp * DD + c) = *(uint4*)o;
        }
    } else {
        // atomic-free fill using captured ranks; rowstart = cb[chunk] + rloc[nd]
        for (int e = (b - NPB) * 256 + tid; e < N_EDGESC; e += NFB * 256) {
            const unsigned int v = tmp[e];
            const int nd = (int)(v & 0xffffu);
            const int p = (int)(v >> 16);
            edata[cb[nd >> 8] + rloc[nd] + p] = src[e] | (etype[e] << 16);
        }
    }
}

// ================= projection GEMM: Xp @ Wall[t] -> KV8 | Qt8 (scatter to orig ids) =================
#define LDP 36

__global__ __launch_bounds__(256) void proj_gemm(
    const ushort* __restrict__ Xp, const ushort* __restrict__ Wall,
    const int* __restrict__ tofs, const int* __restrict__ origof,
    ushort* __restrict__ KV8, unsigned char* __restrict__ Qt8)
{
    const int t = blockIdx.z;
    const int rs = tofs[t], re = tofs[t + 1];
    const int mBase = rs + blockIdx.x * 128;
    if (mBase >= re) return;
    const int nBase = blockIdx.y * 128;
    const ushort* Bt = Wall + (size_t)t * 896 * 128;

    __shared__ ushort As[128 * LDP];
    __shared__ ushort Bs[128 * LDP];
    const int tid = threadIdx.x;
    const int lane = tid & 63, wave = tid >> 6;
    const int mw = (wave >> 1) * 64, nw = (wave & 1) * 64;
    const int l15 = lane & 15, q8 = (lane >> 4) * 8;

    f32x4 acc[4][4];
#pragma unroll
    for (int i = 0; i < 4; i++)
#pragma unroll
        for (int j = 0; j < 4; j++) acc[i][j] = (f32x4){0.f, 0.f, 0.f, 0.f};

    const int r0 = tid >> 2, c0 = (tid & 3) * 8;
    int rA0 = mBase + r0;      if (rA0 >= N_NODESC) rA0 = N_NODESC - 1;
    int rA1 = mBase + r0 + 64; if (rA1 >= N_NODESC) rA1 = N_NODESC - 1;

    for (int kk = 0; kk < 128; kk += 32) {
        short8 a0 = *(const short8*)(Xp + (size_t)rA0 * DD + kk + c0);
        short8 a1 = *(const short8*)(Xp + (size_t)rA1 * DD + kk + c0);
        short8 b0 = *(const short8*)(Bt + (size_t)(nBase + r0) * 128 + kk + c0);
        short8 b1 = *(const short8*)(Bt + (size_t)(nBase + r0 + 64) * 128 + kk + c0);
        *(short8*)&As[r0 * LDP + c0] = a0;
        *(short8*)&As[(r0 + 64) * LDP + c0] = a1;
        *(short8*)&Bs[r0 * LDP + c0] = b0;
        *(short8*)&Bs[(r0 + 64) * LDP + c0] = b1;
        __syncthreads();
        short8 af[4], bf[4];
#pragma unroll
        for (int i = 0; i < 4; i++)
            af[i] = *(const short8*)&As[(mw + i * 16 + l15) * LDP + q8];
#pragma unroll
        for (int j = 0; j < 4; j++)
            bf[j] = *(const short8*)&Bs[(nw + j * 16 + l15) * LDP + q8];
#pragma unroll
        for (int i = 0; i < 4; i++)
#pragma unroll
            for (int j = 0; j < 4; j++)
                acc[i][j] = __builtin_amdgcn_mfma_f32_16x16x32_bf16(af[i], bf[j], acc[i][j], 0, 0, 0);
        __syncthreads();
    }

    unsigned char* kvb = (unsigned char*)KV8;
    const int rq = (lane >> 4) * 4;
#pragma unroll
    for (int i = 0; i < 4; i++) {
#pragma unroll
        for (int r = 0; r < 4; r++) {
            const int gm = mBase + mw + i * 16 + rq + r;
            if (gm >= re) continue;
            const int og = origof[gm];   // scatter outputs to ORIGINAL node id
#pragma unroll
            for (int j = 0; j < 4; j++) {
                const int gn = nBase + nw + j * 16 + l15;
                const float v = acc[i][j][r];
                const unsigned char b8 =
                    (unsigned char)(__builtin_amdgcn_cvt_pk_fp8_f32(v, v, 0, false) & 0xff);
                // planar layout: K plane bytes [0..127], V plane bytes [128..255]
                if (gn < 256) kvb[(size_t)og * 256 + gn] = b8;
                else          Qt8[(size_t)og * 640 + (gn - 256)] = b8;
            }
        }
    }
}

// ================= fused tail v6: edge-agg + LN1-GEMM + FFN + LN2 in ONE kernel ============
// grid 782 x 64-node tiles, 512 threads (8 waves).
// Phase E: each wave aggregates 8 nodes (slot x head lanes) -> writes agg rows DIRECTLY
//          into Ts (the GEMM1 A-tile). No HBM agg buffer, no separate dispatch; edge
//          gather of one block overlaps GEMM phases of co-resident blocks.
// Then: round-6 pipeline (dbuf 64-K panels, raw barriers, fast erf).
#define LDH 132
#define LDB2 68

#define LOADB(P0, P1, PTR) { P0 = *(const short8*)(PTR); P1 = *(const short8*)((PTR) + 8); }
#define STAGEB(BUF, P0, P1) { *(short8*)&Bs[BUF][br * LDB2 + bc] = P0; \
                              *(short8*)&Bs[BUF][br * LDB2 + bc + 8] = P1; }

__global__ __launch_bounds__(512, 4) void fused_tail(
    const int* __restrict__ rows, const int* __restrict__ edata,
    const unsigned char* __restrict__ Qt8, const unsigned char* __restrict__ KV8,
    const ushort* __restrict__ Woutt, const ushort* __restrict__ W1t,
    const ushort* __restrict__ W2t,
    const float* __restrict__ x,
    const float* __restrict__ bout, const float* __restrict__ g1, const float* __restrict__ b1ln,
    const float* __restrict__ b1, const float* __restrict__ b2,
    const float* __restrict__ g2, const float* __restrict__ b2ln,
    float* __restrict__ out)
{
    __shared__ __align__(16) ushort Bs[2][128 * LDB2];   // 2 x 17408 B
    __shared__ __align__(16) ushort Hs[64 * LDH];        // edge q-buf, then h tile
    __shared__ __align__(16) ushort Ts[64 * LDH];        // agg/A-tile, then gelu(t) chunk
    __shared__ float red[2][4][64];

    const int tid = threadIdx.x;
    const int lane = tid & 63, wave = tid >> 6;
    const int wm = wave >> 2, wn = wave & 3;
    const int l15 = lane & 15, q8 = (lane >> 4) * 8, rq = (lane >> 4) * 4;
    const int mBase = blockIdx.x * 64;

    const int br = tid >> 2, bc = (tid & 3) * 16;   // B staging: 128 rows x 64 cols

    // issue long-lived global prefetches FIRST (hidden under the edge phase)
    short8 pX0, pX1, pY0, pY1;
    LOADB(pX0, pX1, Woutt + (size_t)br * 128 + bc);
    LOADB(pY0, pY1, Woutt + (size_t)br * 128 + 64 + bc);
    float xv[2][4][2];
#pragma unroll
    for (int i = 0; i < 2; i++)
#pragma unroll
        for (int r = 0; r < 4; r++) {
            const int gm = mBase + wm * 32 + i * 16 + rq + r;
            const int gr = (gm < N_NODESC) ? gm : N_NODESC - 1;
#pragma unroll
            for (int j = 0; j < 2; j++)
                xv[i][r][j] = x[(size_t)gr * DD + wn * 32 + j * 16 + l15];
        }

    // ================= phase E: edge aggregation, 8 nodes per wave -> Ts rows ==========
    {
        const int slot = lane >> 3;      // 0..7 edge slot
        const int h = lane & 7;          // 0..7 head
        uint* Hqu = (uint*)Hs;           // [8 waves][2 bufs][160 uints] = 10240 B
        const int qbA = wave * 320, qbB = qbA + 160;
        {
            const int nd0 = mBase + wave * 8;
            if (lane < 40 && nd0 < N_NODESC)
                *(uint4*)&Hqu[qbA + lane * 4] =
                    ((const uint4*)(Qt8 + (size_t)nd0 * 640))[lane];
        }
        const float qsc = 1.44269504f / 1024.f;   // log2e / 1024 (fp8 scale folding)
        for (int q = 0; q < 8; q++) {
            const int nd = mBase + wave * 8 + q;
            uint4 nq = make_uint4(0u, 0u, 0u, 0u);
            if (q < 7 && lane < 40 && nd + 1 < N_NODESC)
                nq = ((const uint4*)(Qt8 + (size_t)(nd + 1) * 640))[lane];   // reg relay
            if (nd < N_NODESC) {
                const uint* qbase = &Hqu[(q & 1) ? qbB : qbA];
                const int s0 = rows[nd], s1 = rows[nd + 1];
                float acc[16];
#pragma unroll
                for (int j = 0; j < 16; j++) acc[j] = 0.f;
                float den = 0.f;
                for (int i = s0 + slot; i < s1; i += 8) {
                    const int ed = edata[i];
                    const int sn = ed & 0xffff;
                    const int et = ed >> 16;
                    const unsigned char* kvp = KV8 + ((size_t)sn << 8);
                    const uint4 kw = *(const uint4*)(kvp + (h << 4));
                    const uint4 vw = *(const uint4*)(kvp + 128 + (h << 4));
                    const uint4 qw = *(const uint4*)(qbase + (et << 5) + (h << 2));

                    const f32x2 q0 = pk0(qw.x), q1 = pk1(qw.x), q2 = pk0(qw.y), q3 = pk1(qw.y);
                    const f32x2 q4 = pk0(qw.z), q5 = pk1(qw.z), q6 = pk0(qw.w), q7 = pk1(qw.w);
                    const f32x2 k0 = pk0(kw.x), k1 = pk1(kw.x), k2 = pk0(kw.y), k3 = pk1(kw.y);
                    const f32x2 k4 = pk0(kw.z), k5 = pk1(kw.z), k6 = pk0(kw.w), k7 = pk1(kw.w);

                    float pa = q0.x * k0.x;
                    float pb = q0.y * k0.y;
                    float pc = q1.x * k1.x;
                    float pd = q1.y * k1.y;
                    pa = fmaf(q2.x, k2.x, pa); pb = fmaf(q2.y, k2.y, pb);
                    pc = fmaf(q3.x, k3.x, pc); pd = fmaf(q3.y, k3.y, pd);
                    pa = fmaf(q4.x, k4.x, pa); pb = fmaf(q4.y, k4.y, pb);
                    pc = fmaf(q5.x, k5.x, pc); pd = fmaf(q5.y, k5.y, pd);
                    pa = fmaf(q6.x, k6.x, pa); pb = fmaf(q6.y, k6.y, pb);
                    pc = fmaf(q7.x, k7.x, pc); pd = fmaf(q7.y, k7.y, pd);

                    const float ex = exp2f(((pa + pb) + (pc + pd)) * qsc);
                    den += ex;

                    const f32x2 v0 = pk0(vw.x), v1 = pk1(vw.x), v2 = pk0(vw.y), v3 = pk1(vw.y);
                    const f32x2 v4 = pk0(vw.z), v5 = pk1(vw.z), v6 = pk0(vw.w), v7 = pk1(vw.w);
                    acc[0]  = fmaf(ex, v0.x, acc[0]);  acc[1]  = fmaf(ex, v0.y, acc[1]);
                    acc[2]  = fmaf(ex, v1.x, acc[2]);  acc[3]  = fmaf(ex, v1.y, acc[3]);
                    acc[4]  = fmaf(ex, v2.x, acc[4]);  acc[5]  = fmaf(ex, v2.y, acc[5]);
                    acc[6]  = fmaf(ex, v3.x, acc[6]);  acc[7]  = fmaf(ex, v3.y, acc[7]);
                    acc[8]  = fmaf(ex, v4.x, acc[8]);  acc[9]  = fmaf(ex, v4.y, acc[9]);
                    acc[10] = fmaf(ex, v5.x, acc[10]); acc[11] = fmaf(ex, v5.y, acc[11]);
                    acc[12] = fmaf(ex, v6.x, acc[12]); acc[13] = fmaf(ex, v6.y, acc[13]);
                    acc[14] = fmaf(ex, v7.x, acc[14]); acc[15] = fmaf(ex, v7.y, acc[15]);
                }
                // halving-exchange reduce over 8 slots (lane bits 3,4,5)
                {
                    const int b0 = slot & 1, b1s = slot & 2, b2s = slot & 4;
#pragma unroll
                    for (int j = 0; j < 8; j++) {
                        const float v = b0 ? acc[j] : acc[j + 8];
                        const float r = __shfl_xor(v, 8);
                        acc[j] = (b0 ? acc[j + 8] : acc[j]) + r;
                    }
#pragma unroll
                    for (int j = 0; j < 4; j++) {
                        const float v = b1s ? acc[j] : acc[j + 4];
                        const float r = __shfl_xor(v, 16);
                        acc[j] = (b1s ? acc[j + 4] : acc[j]) + r;
                    }
#pragma unroll
                    for (int j = 0; j < 2; j++) {
                        const float v = b2s ? acc[j] : acc[j + 2];
                        const float r = __shfl_xor(v, 32);
                        acc[j] = (b2s ? acc[j + 2] : acc[j]) + r;
                    }
                    den += __shfl_xor(den, 8);
                    den += __shfl_xor(den, 16);
                    den += __shfl_xor(den, 32);
                }
                const float rr = 0.25f / (den + 1e-10f);   // undo V x4 scale
                const int fb = (h << 4) + ((slot & 1) << 3) + ((slot & 2) << 1) + ((slot & 4) >> 1);
                const int row = wave * 8 + q;
                ushort o2[2] = { f2b(acc[0] * rr), f2b(acc[1] * rr) };
                *(uint*)&Ts[row * LDH + fb] = *(uint*)o2;   // A-tile row, bf16
            }
            if (q < 7 && lane < 40)
                *(uint4*)&Hqu[((q & 1) ? qbA : qbB) + lane * 4] = nq;
        }
    }
    ebar();   // Ts (A-tile) visible block-wide; Hq dead

    f32x4 acc1[2][2], acc2[2][2];
#pragma unroll
    for (int i = 0; i < 2; i++)
#pragma unroll
        for (int j = 0; j < 2; j++) {
            acc1[i][j] = (f32x4){0.f, 0.f, 0.f, 0.f};
            acc2[i][j] = (f32x4){0.f, 0.f, 0.f, 0.f};
        }

    // stage G1a; prefetch F1a0
    STAGEB(0, pX0, pX1);
    LOADB(pX0, pX1, W1t + (size_t)br * 128 + bc);               // F1a0
    ebar();

    // P(G1a): read Bs0 + Ts; stage G1b->Bs1; prefetch F1b0
    STAGEB(1, pY0, pY1);
    LOADB(pY0, pY1, W1t + (size_t)br * 128 + 64 + bc);          // F1b0
#pragma unroll
    for (int kk2 = 0; kk2 < 2; kk2++) {
        short8 af[2], bf[2];
#pragma unroll
        for (int i = 0; i < 2; i++)
            af[i] = *(const short8*)&Ts[(wm * 32 + i * 16 + l15) * LDH + kk2 * 32 + q8];
#pragma unroll
        for (int j = 0; j < 2; j++)
            bf[j] = *(const short8*)&Bs[0][(wn * 32 + j * 16 + l15) * LDB2 + kk2 * 32 + q8];
#pragma unroll
        for (int i = 0; i < 2; i++)
#pragma unroll
            for (int j = 0; j < 2; j++)
                acc1[i][j] = __builtin_amdgcn_mfma_f32_16x16x32_bf16(af[i], bf[j], acc1[i][j], 0, 0, 0);
    }
    ebar();

    // P(G1b): read Bs1 + Ts(k 64..127); stage F1a0->Bs0; prefetch F2a0
    STAGEB(0, pX0, pX1);
    LOADB(pX0, pX1, W2t + (size_t)br * 512 + bc);               // F2a0
#pragma unroll
    for (int kk2 = 0; kk2 < 2; kk2++) {
        short8 af[2], bf[2];
#pragma unroll
        for (int i = 0; i < 2; i++)
            af[i] = *(const short8*)&Ts[(wm * 32 + i * 16 + l15) * LDH + 64 + kk2 * 32 + q8];
#pragma unroll
        for (int j = 0; j < 2; j++)
            bf[j] = *(const short8*)&Bs[1][(wn * 32 + j * 16 + l15) * LDB2 + kk2 * 32 + q8];
#pragma unroll
        for (int i = 0; i < 2; i++)
#pragma unroll
            for (int j = 0; j < 2; j++)
                acc1[i][j] = __builtin_amdgcn_mfma_f32_16x16x32_bf16(af[i], bf[j], acc1[i][j], 0, 0, 0);
    }
    ebar();

    // ---- LN1: h = LN(acc1 + bout + x) -> Hs ----
    {
        float bo[2], gv[2], bv[2];
#pragma unroll
        for (int j = 0; j < 2; j++) {
            const int gn = wn * 32 + j * 16 + l15;
            bo[j] = bout[gn]; gv[j] = g1[gn]; bv[j] = b1ln[gn];
        }
#pragma unroll
        for (int i = 0; i < 2; i++) {
#pragma unroll
            for (int r = 0; r < 4; r++) {
                const int row = wm * 32 + i * 16 + rq + r;
                float s = 0.f, ss = 0.f;
#pragma unroll
                for (int j = 0; j < 2; j++) {
                    float v = acc1[i][j][r] + bo[j] + xv[i][r][j];
                    acc1[i][j][r] = v;
                    s += v; ss += v * v;
                }
                s  += __shfl_xor(s, 1);  s  += __shfl_xor(s, 2);  s  += __shfl_xor(s, 4);  s  += __shfl_xor(s, 8);
                ss += __shfl_xor(ss, 1); ss += __shfl_xor(ss, 2); ss += __shfl_xor(ss, 4); ss += __shfl_xor(ss, 8);
                if (l15 == 0) { red[0][wn][row] = s; red[1][wn][row] = ss; }
            }
        }
        ebar();
#pragma unroll
        for (int i = 0; i < 2; i++) {
#pragma unroll
            for (int r = 0; r < 4; r++) {
                const int row = wm * 32 + i * 16 + rq + r;
                const float s  = red[0][0][row] + red[0][1][row] + red[0][2][row] + red[0][3][row];
                const float ss = red[1][0][row] + red[1][1][row] + red[1][2][row] + red[1][3][row];
                const float mean = s * (1.f / 128.f);
                const float var  = ss * (1.f / 128.f) - mean * mean;
                const float rstd = rsqrtf(var + 1e-5f);
#pragma unroll
                for (int j = 0; j < 2; j++) {
                    const int gn = wn * 32 + j * 16 + l15;
                    Hs[row * LDH + gn] = f2b((acc1[i][j][r] - mean) * rstd * gv[j] + bv[j]);
                }
            }
        }
        ebar();   // publish Hs
    }

    // ---- FFN loop: per nb {F1a, F1b, gelu->Ts, F2a, F2b} ----
    for (int nb = 0; nb < 4; nb++) {
        f32x4 a1[2][2];
#pragma unroll
        for (int i = 0; i < 2; i++)
#pragma unroll
            for (int j = 0; j < 2; j++) a1[i][j] = (f32x4){0.f, 0.f, 0.f, 0.f};

        // P(F1a): read Bs0 + Hs(k 0..63); stage F1b->Bs1; prefetch F2b[nb]
        STAGEB(1, pY0, pY1);
        LOADB(pY0, pY1, W2t + (size_t)br * 512 + nb * 128 + 64 + bc);
#pragma unroll
        for (int kk2 = 0; kk2 < 2; kk2++) {
            short8 af[2], bf[2];
#pragma unroll
            for (int i = 0; i < 2; i++)
                af[i] = *(const short8*)&Hs[(wm * 32 + i * 16 + l15) * LDH + kk2 * 32 + q8];
#pragma unroll
            for (int j = 0; j < 2; j++)
                bf[j] = *(const short8*)&Bs[0][(wn * 32 + j * 16 + l15) * LDB2 + kk2 * 32 + q8];
#pragma unroll
            for (int i = 0; i < 2; i++)
#pragma unroll
                for (int j = 0; j < 2; j++)
                    a1[i][j] = __builtin_amdgcn_mfma_f32_16x16x32_bf16(af[i], bf[j], a1[i][j], 0, 0, 0);
        }
        ebar();

        // P(F1b): read Bs1 + Hs(k 64..127); stage F2a->Bs0; prefetch F1a[nb+1]
        STAGEB(0, pX0, pX1);
        if (nb < 3) { LOADB(pX0, pX1, W1t + (size_t)((nb + 1) * 128 + br) * 128 + bc); }
#pragma unroll
        for (int kk2 = 0; kk2 < 2; kk2++) {
            short8 af[2], bf[2];
#pragma unroll
            for (int i = 0; i < 2; i++)
                af[i] = *(const short8*)&Hs[(wm * 32 + i * 16 + l15) * LDH + 64 + kk2 * 32 + q8];
#pragma unroll
            for (int j = 0; j < 2; j++)
                bf[j] = *(const short8*)&Bs[1][(wn * 32 + j * 16 + l15) * LDB2 + kk2 * 32 + q8];
#pragma unroll
            for (int i = 0; i < 2; i++)
#pragma unroll
                for (int j = 0; j < 2; j++)
                    a1[i][j] = __builtin_amdgcn_mfma_f32_16x16x32_bf16(af[i], bf[j], a1[i][j], 0, 0, 0);
        }
        ebar();

        // gelu -> Ts
        {
            float b1v[2];
#pragma unroll
            for (int j = 0; j < 2; j++)
                b1v[j] = b1[nb * 128 + wn * 32 + j * 16 + l15];
#pragma unroll
            for (int i = 0; i < 2; i++)
#pragma unroll
                for (int j = 0; j < 2; j++)
#pragma unroll
                    for (int r = 0; r < 4; r++) {
                        const int row = wm * 32 + i * 16 + rq + r;
                        const int col = wn * 32 + j * 16 + l15;
                        Ts[row * LDH + col] = f2b(gelu_f(a1[i][j][r] + b1v[j]));
                    }
        }
        ebar();   // publish Ts

        // P(F2a): read Bs0 + Ts(k 0..63); stage F2b->Bs1; prefetch F1b[nb+1]
        STAGEB(1, pY0, pY1);
        if (nb < 3) { LOADB(pY0, pY1, W1t + (size_t)((nb + 1) * 128 + br) * 128 + 64 + bc); }
#pragma unroll
        for (int kk2 = 0; kk2 < 2; kk2++) {
            short8 af[2], bf[2];
#pragma unroll
            for (int i = 0; i < 2; i++)
                af[i] = *(const short8*)&Ts[(wm * 32 + i * 16 + l15) * LDH + kk2 * 32 + q8];
#pragma unroll
            for (int j = 0; j < 2; j++)
                bf[j] = *(const short8*)&Bs[0][(wn * 32 + j * 16 + l15) * LDB2 + kk2 * 32 + q8];
#pragma unroll
            for (int i = 0; i < 2; i++)
#pragma unroll
                for (int j = 0; j < 2; j++)
                    acc2[i][j] = __builtin_amdgcn_mfma_f32_16x16x32_bf16(af[i], bf[j], acc2[i][j], 0, 0, 0);
        }
        ebar();

        // P(F2b): read Bs1 + Ts(k 64..127); stage F1a[nb+1]->Bs0; prefetch F2a[nb+1]
        if (nb < 3) {
            STAGEB(0, pX0, pX1);
            LOADB(pX0, pX1, W2t + (size_t)br * 512 + (nb + 1) * 128 + bc);
        }
#pragma unroll
        for (int kk2 = 0; kk2 < 2; kk2++) {
            short8 af[2], bf[2];
#pragma unroll
            for (int i = 0; i < 2; i++)
                af[i] = *(const short8*)&Ts[(wm * 32 + i * 16 + l15) * LDH + 64 + kk2 * 32 + q8];
#pragma unroll
            for (int j = 0; j < 2; j++)
                bf[j] = *(const short8*)&Bs[1][(wn * 32 + j * 16 + l15) * LDB2 + kk2 * 32 + q8];
#pragma unroll
            for (int i = 0; i < 2; i++)
#pragma unroll
                for (int j = 0; j < 2; j++)
                    acc2[i][j] = __builtin_amdgcn_mfma_f32_16x16x32_bf16(af[i], bf[j], acc2[i][j], 0, 0, 0);
        }
        ebar();
    }

    // ---- LN2: out = LN(acc2 + b2 + h) (f32) ----
    {
        float b2v[2], gv[2], bv[2];
#pragma unroll
        for (int j = 0; j < 2; j++) {
            const int gn = wn * 32 + j * 16 + l15;
            b2v[j] = b2[gn]; gv[j] = g2[gn]; bv[j] = b2ln[gn];
        }
#pragma unroll
        for (int i = 0; i < 2; i++) {
#pragma unroll
            for (int r = 0; r < 4; r++) {
                const int row = wm * 32 + i * 16 + rq + r;
                float s = 0.f, ss = 0.f;
#pragma unroll
                for (int j = 0; j < 2; j++) {
                    const int gn = wn * 32 + j * 16 + l15;
                    float v = acc2[i][j][r] + b2v[j] + b2f(Hs[row * LDH + gn]);
                    acc2[i][j][r] = v;
                    s += v; ss += v * v;
                }
                s  += __shfl_xor(s, 1);  s  += __shfl_xor(s, 2);  s  += __shfl_xor(s, 4);  s  += __shfl_xor(s, 8);
                ss += __shfl_xor(ss, 1); ss += __shfl_xor(ss, 2); ss += __shfl_xor(ss, 4); ss += __shfl_xor(ss, 8);
                if (l15 == 0) { red[0][wn][row] = s; red[1][wn][row] = ss; }
            }
        }
        ebar();
#pragma unroll
        for (int i = 0; i < 2; i++) {
#pragma unroll
            for (int r = 0; r < 4; r++) {
                const int row = wm * 32 + i * 16 + rq + r;
                const int gm = mBase + row;
                if (gm >= N_NODESC) continue;
                const float s  = red[0][0][row] + red[0][1][row] + red[0][2][row] + red[0][3][row];
                const float ss = red[1][0][row] + red[1][1][row] + red[1][2][row] + red[1][3][row];
                const float mean = s * (1.f / 128.f);
                const float var  = ss * (1.f / 128.f) - mean * mean;
                const float rstd = rsqrtf(var + 1e-5f);
#pragma unroll
                for (int j = 0; j < 2; j++) {
                    const int gn = wn * 32 + j * 16 + l15;
                    out[(size_t)gm * DD + gn] = (acc2[i][j][r] - mean) * rstd * gv[j] + bv[j];
                }
            }
        }
    }
}

extern "C" void kernel_launch(void* const* d_in, const int* in_sizes, int n_in,
                              void* d_out, int out_size, void* d_ws, size_t ws_size,
                              hipStream_t stream)
{
    const float* x     = (const float*)d_in[0];
    const int*   ei    = (const int*)d_in[1];
    const int*   etyp  = (const int*)d_in[2];
    const int*   ntype = (const int*)d_in[3];
    const float* Wq    = (const float*)d_in[4];
    const float* Wk    = (const float*)d_in[5];
    const float* Wv    = (const float*)d_in[6];
    const float* We    = (const float*)d_in[7];
    const float* mu    = (const float*)d_in[8];
    const float* Wout  = (const float*)d_in[9];
    const float* bout  = (const float*)d_in[10];
    const float* g1    = (const float*)d_in[11];
    const float* b1ln  = (const float*)d_in[12];
    const float* W1    = (const float*)d_in[13];
    const float* b1    = (const float*)d_in[14];
    const float* W2    = (const float*)d_in[15];
    const float* b2    = (const float*)d_in[16];
    const float* g2    = (const float*)d_in[17];
    const float* b2ln  = (const float*)d_in[18];
    float* out = (float*)d_out;

    char* ws = (char*)d_ws;
    ushort*        KV8   = (ushort*)(ws + KV8_OFF);
    unsigned char* Qt8   = (unsigned char*)(ws + QT8_OFF);
    ushort*        Xp    = (ushort*)(ws + XP_OFF);
    ushort*        Woutt = (ushort*)(ws + WOUTT_OFF);
    ushort*        W1t   = (ushort*)(ws + W1T_OFF);
    ushort*        W2t   = (ushort*)(ws + W2T_OFF);
    ushort*        Wall  = (ushort*)(ws + WALL_OFF);
    int*           edata = (int*)(ws + EDATA_OFF);
    int*           rows  = (int*)(ws + ROWS_OFF);
    int*           origof= (int*)(ws + ORIG_OFF);
    int*           deg   = (int*)(ws + DEG_OFF);
    int*           tofs  = (int*)(ws + TOFS_OFF);
    int*           bh    = (int*)(ws + BH_OFF);
    int*           bb    = (int*)(ws + BB_OFF);
    unsigned int*  tmp   = (unsigned int*)(ws + TMP_OFF);
    int*           rloc  = (int*)(ws + RLOC_OFF);
    int*           csum  = (int*)(ws + CSUM_OFF);

    const int* srcA = ei;
    const int* dstA = ei + N_EDGESC;

    (void)hipMemsetAsync(ws + DEG_OFF, 0, 200000, stream);

    // A: weights | type hist | deg+rank  (independent ranges, one dispatch)
    prep_a<<<1920 + NPB + NEB, 256, 0, stream>>>(
        Wout, W1, W2, Wq, Wk, Wv, We, mu, Woutt, W1t, W2t, Wall,
        ntype, bh, dstA, deg, tmp);
    // B: perm scan | wide chunk-local deg scans
    prep_b<<<1 + NPB, 256, 0, stream>>>(bh, deg, bb, tofs, rloc, csum);
    // C: scatter+Xp+rows | fill edata
    prep_c<<<NPB + NFB, 256, 0, stream>>>(ntype, x, srcA, etyp, bb, rloc, csum, tmp,
                                          origof, Xp, rows, edata);

    proj_gemm<<<dim3(394, 7, 3), 256, 0, stream>>>(Xp, Wall, tofs, origof, KV8, Qt8);

    // merged edge-agg + LN1-GEMM + FFN + LN2 (one kernel, no agg round-trip)
    fused_tail<<<782, 512, 0, stream>>>(rows, edata, Qt8, (const unsigned char*)KV8,
                                        Woutt, W1t, W2t, x,
                                        bout, g1, b1ln, b1, b2, g2, b2ln, out);
}

// Round 8
// 310.306 us; speedup vs baseline: 1.0618x; 1.0618x over previous
//
#include <hip/hip_runtime.h>
#include <hip/hip_bf16.h>

#define N_NODESC 50000
#define N_EDGESC 800000
#define DD 128
#define HH 8
#define HDIM 16
#define N_NT 3
#define N_ET 5
#define NPB 196    // node chunks (196*256 = 50176 >= 50000)
#define NEB 400    // edge-pass blocks in kernel A
#define NFB 512    // fill blocks in kernel C
#define WPB 912    // weight-prep blocks (233472 els / 256)

// ---------------- workspace layout (bytes) ----------------
#define KV8_OFF    ((size_t)0)           // fp8 [N][256] bytes: K plane [0..127], V plane [128..255] (orig ids)
#define QT8_OFF    ((size_t)12800000)    // fp8 [N][640] 32 MB (orig ids, dead after edgeagg)
#define XP_OFF     ((size_t)44800000)    // bf16 [N][128] permuted 12.8 MB (dead after proj)
#define AGG_OFF    ((size_t)57600000)    // bf16 [N][128] 12.8 MB
#define WOUTT_OFF  ((size_t)83200000)    // bf16 [128][128] 32 KB
#define W1T_OFF    ((size_t)83232768)    // bf16 [512][128] 128 KB
#define W2T_OFF    ((size_t)83363840)    // bf16 [128][512] 128 KB
#define WHPF_OFF   ((size_t)83494912)    // bf16 [3][28672] frag-order head-pair weights, 172 KB
#define EDATA_OFF  ((size_t)84183040)    // int [E] packed src|et<<16 (orig ids), 3.2 MB
#define ROWS_OFF   ((size_t)87383040)    // int [N+1] (+pad)
#define ORIG_OFF   ((size_t)87583104)    // int [N]
#define DEG_OFF    ((size_t)87783104)    // int [N] (memset 0)
#define TOFS_OFF   ((size_t)87983104)    // int [4]
#define BH_OFF     ((size_t)87983168)    // int [3*NPB]
#define BB_OFF     ((size_t)87985536)    // int [3*NPB]
#define TMP_OFF    ((size_t)87988928)    // uint [E] packed rank<<16|nd, 3.2 MB
#define RLOC_OFF   ((size_t)91188928)    // int [N+1] chunk-local exclusive deg scan
#define CSUM_OFF   ((size_t)91389056)    // int [NPB] per-chunk deg sums

using short8 = __attribute__((ext_vector_type(8))) short;
using f32x4  = __attribute__((ext_vector_type(4))) float;
using f32x2  = __attribute__((ext_vector_type(2))) float;

__device__ __forceinline__ ushort f2b(float f) {
    __hip_bfloat16 h = __float2bfloat16(f);
    return *(ushort*)&h;
}
__device__ __forceinline__ float b2f(ushort u) {
    __hip_bfloat16 h = *(__hip_bfloat16*)&u;
    return __bfloat162float(h);
}
__device__ __forceinline__ f32x2 pk0(unsigned int w) {
    return __builtin_amdgcn_cvt_pk_f32_fp8((int)w, false);   // bytes 0,1
}
__device__ __forceinline__ f32x2 pk1(unsigned int w) {
    return __builtin_amdgcn_cvt_pk_f32_fp8((int)w, true);    // bytes 2,3
}
// exact-form gelu with A&S 7.1.26 erf approx (|err_erf| < 1.6e-7, far below bf16 lsb)
__device__ __forceinline__ float gelu_f(float v) {
    const float x = v * 0.70710678118654752f;
    const float ax = fabsf(x);
    const float d = fmaf(0.3275911f, ax, 1.0f);
    float t;
    asm("v_rcp_f32 %0, %1" : "=v"(t) : "v"(d));
    float p = fmaf(1.061405429f, t, -1.453152027f);
    p = fmaf(p, t, 1.421413741f);
    p = fmaf(p, t, -0.284496736f);
    p = fmaf(p, t, 0.254829592f);
    p = p * t;
    const float e = __expf(-ax * ax);
    const float er = 1.0f - p * e;
    const float erfx = (x < 0.f) ? -er : er;
    return 0.5f * v * (1.0f + erfx);
}
// raw barrier: waits only LDS (lgkmcnt), NOT vmcnt -- in-flight global prefetch survives.
__device__ __forceinline__ void ebar() {
    __builtin_amdgcn_sched_barrier(0);
    asm volatile("s_waitcnt lgkmcnt(0)" ::: "memory");
    __builtin_amdgcn_sched_barrier(0);
    __builtin_amdgcn_s_barrier();
    __builtin_amdgcn_sched_barrier(0);
}

// ================= kernel A: wprep (b<WPB) | phist | deg+rank (rest) =================
__global__ __launch_bounds__(256) void prep_a(
    const float* __restrict__ Wout, const float* __restrict__ W1, const float* __restrict__ W2,
    const float* __restrict__ WQ, const float* __restrict__ Wk, const float* __restrict__ Wv,
    const float* __restrict__ We, const float* __restrict__ mu,
    ushort* __restrict__ Woutt, ushort* __restrict__ W1t, ushort* __restrict__ W2t,
    ushort* __restrict__ Whpf,
    const int* __restrict__ ntype, int* __restrict__ bh,
    const int* __restrict__ dst, int* __restrict__ deg, unsigned int* __restrict__ tmp)
{
    const int b = blockIdx.x, tid = threadIdx.x;
    if (b < WPB) {
        const int gid = b * 256 + tid;
        if (gid < 16384) {                       // Woutt[n][k] = Wout[k][n]
            const int nn = gid >> 7, k = gid & 127;
            Woutt[gid] = f2b(Wout[k * 128 + nn]);
        } else if (gid < 81920) {                // W1t[n][k] = W1[k][n]
            const int i = gid - 16384;
            const int nn = i >> 7, k = i & 127;
            W1t[i] = f2b(W1[k * 512 + nn]);
        } else if (gid < 147456) {               // W2t[n][k] = W2[k][n]
            const int i = gid - 81920;
            const int nn = i >> 9, k = i & 511;
            W2t[i] = f2b(W2[k * 128 + nn]);
        } else {
            // Whpf: MFMA B-fragment-order head-pair weights.
            // [t][p(4)][j(14)][lane(64)][i(8)]: col c=j*16+(lane&15) in pair-local 224
            // (head 2p if c<112 else 2p+1), k=(lane>>4)*8+i in pair's 32 input dims.
            // Zero when k's head half != col's head (block-diagonal).
            const int idx = gid - 147456;        // < 86016
            const int t = idx / 28672;
            const int r = idx % 28672;
            const int i = r & 7;
            const int l = (r >> 3) & 63;
            const int f = r >> 9;                // 0..55
            const int j = f % 14, p = f / 14;
            const int c = j * 16 + (l & 15);     // 0..223
            const int k = ((l >> 4) << 3) + i;   // 0..31
            const int hi = (c >= 112) ? 1 : 0;
            const int h = 2 * p + hi;
            float v = 0.f;
            if ((k >> 4) == hi) {
                const int kp = k & 15;
                const int cl = c - hi * 112;     // 0..111
                if (cl < 16) {
                    v = 4.f * Wk[((t * HH + h) * HDIM + kp) * HDIM + cl];
                } else if (cl < 32) {
                    v = 4.f * Wv[((t * HH + h) * HDIM + kp) * HDIM + (cl - 16)];
                } else {
                    const int et = (cl - 32) >> 4, jj = (cl - 32) & 15;
                    const float* wq = WQ + ((t * HH + h) * HDIM + kp) * HDIM;
                    const float* we = We + ((et * HH + h) * HDIM + jj) * HDIM;
                    float s = 0.f;
#pragma unroll
                    for (int ff = 0; ff < 16; ff++) s = fmaf(wq[ff], we[ff], s);
                    v = 64.f * mu[h * N_ET + et] * s;   // 64 = 256 fp8 scale * 0.25
                }
            }
            Whpf[idx] = f2b(v);
        }
    } else if (b < WPB + NPB) {
        const int bc = b - WPB;
        const int wave = tid >> 6, lane = tid & 63;
        const int n = bc * 256 + tid;
        const int t = (n < N_NODESC) ? ntype[n] : -1;
        const unsigned long long m0 = __ballot(t == 0);
        const unsigned long long m1 = __ballot(t == 1);
        const unsigned long long m2 = __ballot(t == 2);
        __shared__ int wcnt[4][3];
        if (lane == 0) {
            wcnt[wave][0] = (int)__popcll(m0);
            wcnt[wave][1] = (int)__popcll(m1);
            wcnt[wave][2] = (int)__popcll(m2);
        }
        __syncthreads();
        if (tid < 3)
            bh[tid * NPB + bc] = wcnt[0][tid] + wcnt[1][tid] + wcnt[2][tid] + wcnt[3][tid];
    } else {
        for (int e = (b - WPB - NPB) * 256 + tid; e < N_EDGESC; e += NEB * 256) {
            const int nd = dst[e];
            const unsigned int p = (unsigned int)atomicAdd(&deg[nd], 1);
            tmp[e] = (p << 16) | (unsigned int)nd;
        }
    }
}

// ================= kernel B: permscan (block 0) | WIDE chunk-local deg scans (1..196) ============
__global__ __launch_bounds__(256) void prep_b(
    const int* __restrict__ bh, const int* __restrict__ deg,
    int* __restrict__ bb, int* __restrict__ tofs,
    int* __restrict__ rloc, int* __restrict__ csum)
{
    __shared__ int part[256];
    const int tid = threadIdx.x;
    if (blockIdx.x == 0) {
        // exclusive scan of 3*NPB=588 entries: 3 per thread
        const int base3 = tid * 3;
        int e0 = (base3 + 0 < 588) ? bh[base3 + 0] : 0;
        int e1 = (base3 + 1 < 588) ? bh[base3 + 1] : 0;
        int e2 = (base3 + 2 < 588) ? bh[base3 + 2] : 0;
        const int l0 = e0, l1 = e0 + e1, l2 = l1 + e2;
        part[tid] = l2;
        __syncthreads();
        for (int off = 1; off < 256; off <<= 1) {
            const int u = (tid >= off) ? part[tid - off] : 0;
            __syncthreads();
            part[tid] += u;
            __syncthreads();
        }
        const int tb = part[tid] - l2;
        if (base3 + 0 < 588) bb[base3 + 0] = tb;
        if (base3 + 1 < 588) bb[base3 + 1] = tb + l0;
        if (base3 + 2 < 588) bb[base3 + 2] = tb + l1;
        __syncthreads();
        if (tid == 0) {
            tofs[0] = 0;
            tofs[1] = bb[NPB];
            tofs[2] = bb[2 * NPB];
            tofs[3] = N_NODESC;
        }
    } else {
        // chunk-local exclusive scan (coalesced): chunk c covers nodes c*256..c*256+255
        const int c = blockIdx.x - 1;
        const int n = c * 256 + tid;
        const int vdeg = (n < N_NODESC) ? deg[n] : 0;
        part[tid] = vdeg;
        __syncthreads();
        for (int off = 1; off < 256; off <<= 1) {
            const int u = (tid >= off) ? part[tid - off] : 0;
            __syncthreads();
            part[tid] += u;
            __syncthreads();
        }
        if (n <= N_NODESC) rloc[n] = part[tid] - vdeg;   // includes rloc[N]
        if (tid == 255) csum[c] = part[255];
    }
}

// ================= kernel C: pscatter+Xp+rows (b<NPB) | fill edata (rest) =================
__global__ __launch_bounds__(256) void prep_c(
    const int* __restrict__ ntype, const float* __restrict__ x,
    const int* __restrict__ src, const int* __restrict__ etype,
    const int* __restrict__ bb, const int* __restrict__ rloc, const int* __restrict__ csum,
    const unsigned int* __restrict__ tmp,
    int* __restrict__ origof, ushort* __restrict__ Xp, int* __restrict__ rows,
    int* __restrict__ edata)
{
    const int b = blockIdx.x, tid = threadIdx.x;
    __shared__ int cb[256];   // exclusive chunk bases
    // every block: LDS scan of csum[196] -> exclusive bases (tiny, redundant, parallel)
    {
        const int v = (tid < NPB) ? csum[tid] : 0;
        cb[tid] = v;
        __syncthreads();
        for (int off = 1; off < 256; off <<= 1) {
            const int u = (tid >= off) ? cb[tid - off] : 0;
            __syncthreads();
            cb[tid] += u;
            __syncthreads();
        }
        const int incl = cb[tid];
        __syncthreads();
        cb[tid] = incl - v;   // exclusive
        __syncthreads();
    }

    if (b < NPB) {
        const int wave = tid >> 6, lane = tid & 63;
        const int n = b * 256 + tid;
        const int t = (n < N_NODESC) ? ntype[n] : -1;
        const unsigned long long m0 = __ballot(t == 0);
        const unsigned long long m1 = __ballot(t == 1);
        const unsigned long long m2 = __ballot(t == 2);
        __shared__ int wcnt[4][3];
        __shared__ int sp[256];
        if (lane == 0) {
            wcnt[wave][0] = (int)__popcll(m0);
            wcnt[wave][1] = (int)__popcll(m1);
            wcnt[wave][2] = (int)__popcll(m2);
        }
        __syncthreads();
        int p = -1;
        if (n < N_NODESC) {
            int basew = 0;
#pragma unroll
            for (int w = 0; w < 4; w++) if (w < wave) basew += wcnt[w][t];
            const unsigned long long mt = (t == 0) ? m0 : (t == 1) ? m1 : m2;
            const unsigned long long mlt = ((unsigned long long)1 << lane) - 1;
            p = bb[t * NPB + b] + basew + (int)__popcll(mt & mlt);
            origof[p] = n;
        }
        // final rows for this chunk (rloc[n] + chunk base); includes rows[N] from chunk 195
        if (n <= N_NODESC) rows[n] = cb[b] + rloc[n];
        sp[tid] = p;
        __syncthreads();
        // cooperative permuted bf16 copy: 256 nodes x 16 chunks of 8
        for (int i = tid; i < 256 * 16; i += 256) {
            const int nn = i >> 4, c = (i & 15) << 3;
            const int pp = sp[nn];
            if (pp < 0) continue;
            const int n2 = b * 256 + nn;
            const float4 v0 = *(const float4*)(x + (size_t)n2 * DD + c);
            const float4 v1 = *(const float4*)(x + (size_t)n2 * DD + c + 4);
            ushort o[8] = {f2b(v0.x), f2b(v0.y), f2b(v0.z), f2b(v0.w),
                           f2b(v1.x), f2b(v1.y), f2b(v1.z), f2b(v1.w)};
            *(uint4*)(Xp + (size_t)pp * DD + c) = *(uint4*)o;
        }
    } else {
        // atomic-free fill using captured ranks; rowstart = cb[chunk] + rloc[nd]
        for (int e = (b - NPB) * 256 + tid; e < N_EDGESC; e += NFB * 256) {
            const unsigned int v = tmp[e];
            const int nd = (int)(v & 0xffffu);
            const int p = (int)(v >> 16);
            edata[cb[nd >> 8] + rloc[nd] + p] = src[e] | (etype[e] << 16);
        }
    }
}

// ================= proj v2: per-head-pair K=32 MFMA (block-diag aware, 4x fewer MFMA) ===========
// 64 permuted rows per block; stage Xp tile + per-type frag-order weights once; each output
// 16x16 fragment = ONE mfma (K=32 covers its head-pair's input dims). Epilogue section is
// uniform per (p,j): j%7==0 -> K, ==1 -> V, else Qt[et=j%7-2].
#define LDX 132

__global__ __launch_bounds__(256) void proj_gemm(
    const ushort* __restrict__ Xp, const ushort* __restrict__ Whpf,
    const int* __restrict__ tofs, const int* __restrict__ origof,
    unsigned char* __restrict__ KV8b, unsigned char* __restrict__ Qt8)
{
    const int t = blockIdx.y;
    const int rs = tofs[t], re = tofs[t + 1];
    const int mBase = rs + blockIdx.x * 64;
    if (mBase >= re) return;

    __shared__ ushort Xs[64 * LDX];      // 16896 B
    __shared__ ushort Ws[28672];         // 57344 B (frag-order, linear copy)

    const int tid = threadIdx.x;
    const int lane = tid & 63, wave = tid >> 6;
    const int l15 = lane & 15, rq = (lane >> 4) * 4;

    // stage Xp tile (coalesced): 64 rows x 16 chunks of 16B
#pragma unroll
    for (int it = 0; it < 4; it++) {
        const int idx = it * 256 + tid;
        const int row = idx >> 4, ch = idx & 15;
        int gr = mBase + row; if (gr >= N_NODESC) gr = N_NODESC - 1;
        *(uint4*)&Xs[row * LDX + ch * 8] = *(const uint4*)(Xp + (size_t)gr * DD + ch * 8);
    }
    // stage weight fragments (linear)
    const ushort* Wg = Whpf + (size_t)t * 28672;
#pragma unroll
    for (int it = 0; it < 14; it++) {
        const int idx = it * 256 + tid;
        *(uint4*)&Ws[idx * 8] = *(const uint4*)(Wg + (size_t)idx * 8);
    }
    __syncthreads();

    int ogr[4]; bool vr[4];
#pragma unroll
    for (int r = 0; r < 4; r++) {
        const int gm = mBase + wave * 16 + rq + r;
        vr[r] = (gm < re);
        ogr[r] = vr[r] ? origof[gm] : 0;
    }

    for (int p = 0; p < 4; p++) {
        const short8 af = *(const short8*)&Xs[(wave * 16 + l15) * LDX + p * 32 + (lane >> 4) * 8];
#pragma unroll
        for (int j = 0; j < 14; j++) {
            const short8 bf = *(const short8*)&Ws[((p * 14 + j) * 64 + lane) * 8];
            f32x4 c = __builtin_amdgcn_mfma_f32_16x16x32_bf16(
                af, bf, (f32x4){0.f, 0.f, 0.f, 0.f}, 0, 0, 0);
            const int hi = (j >= 7) ? 1 : 0;
            const int h = 2 * p + hi;
            const int jj = j - hi * 7;           // 0:K 1:V 2..6:Qt[et]
#pragma unroll
            for (int r = 0; r < 4; r++) {
                if (!vr[r]) continue;
                const float v = c[r];
                const unsigned char b8 =
                    (unsigned char)(__builtin_amdgcn_cvt_pk_fp8_f32(v, v, 0, false) & 0xff);
                const size_t og = (size_t)ogr[r];
                if (jj == 0)      KV8b[og * 256 + h * 16 + l15] = b8;
                else if (jj == 1) KV8b[og * 256 + 128 + h * 16 + l15] = b8;
                else              Qt8[og * 640 + (jj - 2) * 128 + h * 16 + l15] = b8;
            }
        }
    }
}

// ================= fused edge pass, per-(edge,head) lane ownership =================
__global__ __launch_bounds__(128) void edgeagg_kernel(
    const int* __restrict__ rowstart, const int* __restrict__ edata,
    const unsigned char* __restrict__ Qt8, const unsigned char* __restrict__ KV8,
    ushort* __restrict__ agg)
{
    const int w = threadIdx.x >> 6;
    const int lane = threadIdx.x & 63;
    const int n = blockIdx.x * 2 + w;
    const int slot = lane >> 3;      // 0..7 edge slot
    const int h = lane & 7;          // 0..7 head

    __shared__ uint4 qs8s[2][40];    // fp8 q row: [et 0..4][128 features], 640 B per wave
    if (lane < 40)
        qs8s[w][lane] = ((const uint4*)(Qt8 + (size_t)n * 640))[lane];
    __syncthreads();
    const uint* qbase = (const uint*)&qs8s[w][0];

    const int s0 = rowstart[n], s1 = rowstart[n + 1];
    const float qsc = 1.44269504f / 1024.f;   // log2e / 1024 (fp8 scale folding)

    float acc[16];
#pragma unroll
    for (int j = 0; j < 16; j++) acc[j] = 0.f;
    float den = 0.f;

    for (int i = s0 + slot; i < s1; i += 8) {
        const int ed = edata[i];
        const int sn = ed & 0xffff;
        const int et = ed >> 16;
        const unsigned char* kvp = KV8 + ((size_t)sn << 8);
        const uint4 kw = *(const uint4*)(kvp + (h << 4));          // K fp8 x16, head h
        const uint4 vw = *(const uint4*)(kvp + 128 + (h << 4));    // V fp8 x16, head h
        const uint4 qw = *(const uint4*)(qbase + (et << 5) + (h << 2));  // q fp8 x16

        const f32x2 q0 = pk0(qw.x), q1 = pk1(qw.x), q2 = pk0(qw.y), q3 = pk1(qw.y);
        const f32x2 q4 = pk0(qw.z), q5 = pk1(qw.z), q6 = pk0(qw.w), q7 = pk1(qw.w);
        const f32x2 k0 = pk0(kw.x), k1 = pk1(kw.x), k2 = pk0(kw.y), k3 = pk1(kw.y);
        const f32x2 k4 = pk0(kw.z), k5 = pk1(kw.z), k6 = pk0(kw.w), k7 = pk1(kw.w);

        float pa = q0.x * k0.x;
        float pb = q0.y * k0.y;
        float pc = q1.x * k1.x;
        float pd = q1.y * k1.y;
        pa = fmaf(q2.x, k2.x, pa); pb = fmaf(q2.y, k2.y, pb);
        pc = fmaf(q3.x, k3.x, pc); pd = fmaf(q3.y, k3.y, pd);
        pa = fmaf(q4.x, k4.x, pa); pb = fmaf(q4.y, k4.y, pb);
        pc = fmaf(q5.x, k5.x, pc); pd = fmaf(q5.y, k5.y, pd);
        pa = fmaf(q6.x, k6.x, pa); pb = fmaf(q6.y, k6.y, pb);
        pc = fmaf(q7.x, k7.x, pc); pd = fmaf(q7.y, k7.y, pd);

        const float ex = exp2f(((pa + pb) + (pc + pd)) * qsc);
        den += ex;

        const f32x2 v0 = pk0(vw.x), v1 = pk1(vw.x), v2 = pk0(vw.y), v3 = pk1(vw.y);
        const f32x2 v4 = pk0(vw.z), v5 = pk1(vw.z), v6 = pk0(vw.w), v7 = pk1(vw.w);
        acc[0]  = fmaf(ex, v0.x, acc[0]);  acc[1]  = fmaf(ex, v0.y, acc[1]);
        acc[2]  = fmaf(ex, v1.x, acc[2]);  acc[3]  = fmaf(ex, v1.y, acc[3]);
        acc[4]  = fmaf(ex, v2.x, acc[4]);  acc[5]  = fmaf(ex, v2.y, acc[5]);
        acc[6]  = fmaf(ex, v3.x, acc[6]);  acc[7]  = fmaf(ex, v3.y, acc[7]);
        acc[8]  = fmaf(ex, v4.x, acc[8]);  acc[9]  = fmaf(ex, v4.y, acc[9]);
        acc[10] = fmaf(ex, v5.x, acc[10]); acc[11] = fmaf(ex, v5.y, acc[11]);
        acc[12] = fmaf(ex, v6.x, acc[12]); acc[13] = fmaf(ex, v6.y, acc[13]);
        acc[14] = fmaf(ex, v7.x, acc[14]); acc[15] = fmaf(ex, v7.y, acc[15]);
    }

    // halving-exchange reduce over the 8 slots sharing head h (lane bits 3,4,5).
    {
        const int b0 = slot & 1, b1 = slot & 2, b2 = slot & 4;
#pragma unroll
        for (int j = 0; j < 8; j++) {
            const float v = b0 ? acc[j] : acc[j + 8];
            const float r = __shfl_xor(v, 8);
            acc[j] = (b0 ? acc[j + 8] : acc[j]) + r;
        }
#pragma unroll
        for (int j = 0; j < 4; j++) {
            const float v = b1 ? acc[j] : acc[j + 4];
            const float r = __shfl_xor(v, 16);
            acc[j] = (b1 ? acc[j + 4] : acc[j]) + r;
        }
#pragma unroll
        for (int j = 0; j < 2; j++) {
            const float v = b2 ? acc[j] : acc[j + 2];
            const float r = __shfl_xor(v, 32);
            acc[j] = (b2 ? acc[j + 2] : acc[j]) + r;
        }
        den += __shfl_xor(den, 8);
        den += __shfl_xor(den, 16);
        den += __shfl_xor(den, 32);
    }
    const float rr = 0.25f / (den + 1e-10f);   // undo V x4 scale
    const int fb = (h << 4) + ((slot & 1) << 3) + ((slot & 2) << 1) + ((slot & 4) >> 1);
    ushort o2[2] = { f2b(acc[0] * rr), f2b(acc[1] * rr) };
    *(uint*)&agg[((size_t)n << 7) + fb] = *(uint*)o2;
}

// ================= fused tail v5: 8 waves, dbuf 64-K panels, one ebar per half-phase ============
#define LDH 132
#define LDB2 68

#define LOADB(P0, P1, PTR) { P0 = *(const short8*)(PTR); P1 = *(const short8*)((PTR) + 8); }
#define STAGEB(BUF, P0, P1) { *(short8*)&Bs[BUF][br * LDB2 + bc] = P0; \
                              *(short8*)&Bs[BUF][br * LDB2 + bc + 8] = P1; }

__global__ __launch_bounds__(512, 4) void fused_tail(
    const ushort* __restrict__ agg, const ushort* __restrict__ Woutt,
    const ushort* __restrict__ W1t, const ushort* __restrict__ W2t,
    const float* __restrict__ x,
    const float* __restrict__ bout, const float* __restrict__ g1, const float* __restrict__ b1ln,
    const float* __restrict__ b1, const float* __restrict__ b2,
    const float* __restrict__ g2, const float* __restrict__ b2ln,
    float* __restrict__ out)
{
    __shared__ ushort Bs[2][128 * LDB2];   // 2 x 17408 B
    __shared__ ushort Hs[64 * LDH];        // h tile (LN1 out; FFN1 A; LN2 residual)
    __shared__ ushort Ts[64 * LDH];        // GEMM1 A-tile, then gelu(t) chunk (FFN2 A)
    __shared__ float red[2][4][64];

    const int tid = threadIdx.x;
    const int lane = tid & 63, wave = tid >> 6;
    const int wm = wave >> 2, wn = wave & 3;
    const int l15 = lane & 15, q8 = (lane >> 4) * 8, rq = (lane >> 4) * 4;
    const int mBase = blockIdx.x * 64;

    const int br = tid >> 2, bc = (tid & 3) * 16;   // B staging: 128 rows x 64 cols
    const int ar = tid >> 3, ac = (tid & 7) * 16;   // A staging: 64 rows x 128 cols
    int rowA = mBase + ar; if (rowA >= N_NODESC) rowA = N_NODESC - 1;

    f32x4 acc1[2][2], acc2[2][2];
#pragma unroll
    for (int i = 0; i < 2; i++)
#pragma unroll
        for (int j = 0; j < 2; j++) {
            acc1[i][j] = (f32x4){0.f, 0.f, 0.f, 0.f};
            acc2[i][j] = (f32x4){0.f, 0.f, 0.f, 0.f};
        }

    // prologue: load G1a->pX, G1b->pY, A-tile; stage A + G1a; prefetch F1a0->pX
    short8 pX0, pX1, pY0, pY1, aT0, aT1;
    LOADB(pX0, pX1, Woutt + (size_t)br * 128 + bc);
    LOADB(pY0, pY1, Woutt + (size_t)br * 128 + 64 + bc);
    aT0 = *(const short8*)(agg + (size_t)rowA * DD + ac);
    aT1 = *(const short8*)(agg + (size_t)rowA * DD + ac + 8);
    float xv[2][4][2];
#pragma unroll
    for (int i = 0; i < 2; i++)
#pragma unroll
        for (int r = 0; r < 4; r++) {
            const int gm = mBase + wm * 32 + i * 16 + rq + r;
            const int gr = (gm < N_NODESC) ? gm : N_NODESC - 1;
#pragma unroll
            for (int j = 0; j < 2; j++)
                xv[i][r][j] = x[(size_t)gr * DD + wn * 32 + j * 16 + l15];
        }
    *(short8*)&Ts[ar * LDH + ac] = aT0;
    *(short8*)&Ts[ar * LDH + ac + 8] = aT1;
    STAGEB(0, pX0, pX1);
    LOADB(pX0, pX1, W1t + (size_t)br * 128 + bc);               // F1a0
    ebar();

    // P(G1a): read Bs0 + Ts; stage G1b->Bs1; prefetch F1b0
    STAGEB(1, pY0, pY1);
    LOADB(pY0, pY1, W1t + (size_t)br * 128 + 64 + bc);          // F1b0
#pragma unroll
    for (int kk2 = 0; kk2 < 2; kk2++) {
        short8 af[2], bf[2];
#pragma unroll
        for (int i = 0; i < 2; i++)
            af[i] = *(const short8*)&Ts[(wm * 32 + i * 16 + l15) * LDH + kk2 * 32 + q8];
#pragma unroll
        for (int j = 0; j < 2; j++)
            bf[j] = *(const short8*)&Bs[0][(wn * 32 + j * 16 + l15) * LDB2 + kk2 * 32 + q8];
#pragma unroll
        for (int i = 0; i < 2; i++)
#pragma unroll
            for (int j = 0; j < 2; j++)
                acc1[i][j] = __builtin_amdgcn_mfma_f32_16x16x32_bf16(af[i], bf[j], acc1[i][j], 0, 0, 0);
    }
    ebar();

    // P(G1b): read Bs1 + Ts(k 64..127); stage F1a0->Bs0; prefetch F2a0
    STAGEB(0, pX0, pX1);
    LOADB(pX0, pX1, W2t + (size_t)br * 512 + bc);               // F2a0
#pragma unroll
    for (int kk2 = 0; kk2 < 2; kk2++) {
        short8 af[2], bf[2];
#pragma unroll
        for (int i = 0; i < 2; i++)
            af[i] = *(const short8*)&Ts[(wm * 32 + i * 16 + l15) * LDH + 64 + kk2 * 32 + q8];
#pragma unroll
        for (int j = 0; j < 2; j++)
            bf[j] = *(const short8*)&Bs[1][(wn * 32 + j * 16 + l15) * LDB2 + kk2 * 32 + q8];
#pragma unroll
        for (int i = 0; i < 2; i++)
#pragma unroll
            for (int j = 0; j < 2; j++)
                acc1[i][j] = __builtin_amdgcn_mfma_f32_16x16x32_bf16(af[i], bf[j], acc1[i][j], 0, 0, 0);
    }
    ebar();

    // ---- LN1: h = LN(acc1 + bout + x) -> Hs ----
    {
        float bo[2], gv[2], bv[2];
#pragma unroll
        for (int j = 0; j < 2; j++) {
            const int gn = wn * 32 + j * 16 + l15;
            bo[j] = bout[gn]; gv[j] = g1[gn]; bv[j] = b1ln[gn];
        }
#pragma unroll
        for (int i = 0; i < 2; i++) {
#pragma unroll
            for (int r = 0; r < 4; r++) {
                const int row = wm * 32 + i * 16 + rq + r;
                float s = 0.f, ss = 0.f;
#pragma unroll
                for (int j = 0; j < 2; j++) {
                    float v = acc1[i][j][r] + bo[j] + xv[i][r][j];
                    acc1[i][j][r] = v;
                    s += v; ss += v * v;
                }
                s  += __shfl_xor(s, 1);  s  += __shfl_xor(s, 2);  s  += __shfl_xor(s, 4);  s  += __shfl_xor(s, 8);
                ss += __shfl_xor(ss, 1); ss += __shfl_xor(ss, 2); ss += __shfl_xor(ss, 4); ss += __shfl_xor(ss, 8);
                if (l15 == 0) { red[0][wn][row] = s; red[1][wn][row] = ss; }
            }
        }
        ebar();
#pragma unroll
        for (int i = 0; i < 2; i++) {
#pragma unroll
            for (int r = 0; r < 4; r++) {
                const int row = wm * 32 + i * 16 + rq + r;
                const float s  = red[0][0][row] + red[0][1][row] + red[0][2][row] + red[0][3][row];
                const float ss = red[1][0][row] + red[1][1][row] + red[1][2][row] + red[1][3][row];
                const float mean = s * (1.f / 128.f);
                const float var  = ss * (1.f / 128.f) - mean * mean;
                const float rstd = rsqrtf(var + 1e-5f);
#pragma unroll
                for (int j = 0; j < 2; j++) {
                    const int gn = wn * 32 + j * 16 + l15;
                    Hs[row * LDH + gn] = f2b((acc1[i][j][r] - mean) * rstd * gv[j] + bv[j]);
                }
            }
        }
        ebar();   // publish Hs
    }

    // ---- FFN loop: per nb {F1a, F1b, gelu->Ts, F2a, F2b} ----
    for (int nb = 0; nb < 4; nb++) {
        f32x4 a1[2][2];
#pragma unroll
        for (int i = 0; i < 2; i++)
#pragma unroll
            for (int j = 0; j < 2; j++) a1[i][j] = (f32x4){0.f, 0.f, 0.f, 0.f};

        // P(F1a): read Bs0 + Hs(k 0..63); stage F1b->Bs1; prefetch F2b[nb]
        STAGEB(1, pY0, pY1);
        LOADB(pY0, pY1, W2t + (size_t)br * 512 + nb * 128 + 64 + bc);
#pragma unroll
        for (int kk2 = 0; kk2 < 2; kk2++) {
            short8 af[2], bf[2];
#pragma unroll
            for (int i = 0; i < 2; i++)
                af[i] = *(const short8*)&Hs[(wm * 32 + i * 16 + l15) * LDH + kk2 * 32 + q8];
#pragma unroll
            for (int j = 0; j < 2; j++)
                bf[j] = *(const short8*)&Bs[0][(wn * 32 + j * 16 + l15) * LDB2 + kk2 * 32 + q8];
#pragma unroll
            for (int i = 0; i < 2; i++)
#pragma unroll
                for (int j = 0; j < 2; j++)
                    a1[i][j] = __builtin_amdgcn_mfma_f32_16x16x32_bf16(af[i], bf[j], a1[i][j], 0, 0, 0);
        }
        ebar();

        // P(F1b): read Bs1 + Hs(k 64..127); stage F2a->Bs0; prefetch F1a[nb+1]
        STAGEB(0, pX0, pX1);
        if (nb < 3) { LOADB(pX0, pX1, W1t + (size_t)((nb + 1) * 128 + br) * 128 + bc); }
#pragma unroll
        for (int kk2 = 0; kk2 < 2; kk2++) {
            short8 af[2], bf[2];
#pragma unroll
            for (int i = 0; i < 2; i++)
                af[i] = *(const short8*)&Hs[(wm * 32 + i * 16 + l15) * LDH + 64 + kk2 * 32 + q8];
#pragma unroll
            for (int j = 0; j < 2; j++)
                bf[j] = *(const short8*)&Bs[1][(wn * 32 + j * 16 + l15) * LDB2 + kk2 * 32 + q8];
#pragma unroll
            for (int i = 0; i < 2; i++)
#pragma unroll
                for (int j = 0; j < 2; j++)
                    a1[i][j] = __builtin_amdgcn_mfma_f32_16x16x32_bf16(af[i], bf[j], a1[i][j], 0, 0, 0);
        }
        ebar();

        // gelu -> Ts
        {
            float b1v[2];
#pragma unroll
            for (int j = 0; j < 2; j++)
                b1v[j] = b1[nb * 128 + wn * 32 + j * 16 + l15];
#pragma unroll
            for (int i = 0; i < 2; i++)
#pragma unroll
                for (int j = 0; j < 2; j++)
#pragma unroll
                    for (int r = 0; r < 4; r++) {
                        const int row = wm * 32 + i * 16 + rq + r;
                        const int col = wn * 32 + j * 16 + l15;
                        Ts[row * LDH + col] = f2b(gelu_f(a1[i][j][r] + b1v[j]));
                    }
        }
        ebar();   // publish Ts

        // P(F2a): read Bs0 + Ts(k 0..63); stage F2b->Bs1; prefetch F1b[nb+1]
        STAGEB(1, pY0, pY1);
        if (nb < 3) { LOADB(pY0, pY1, W1t + (size_t)((nb + 1) * 128 + br) * 128 + 64 + bc); }
#pragma unroll
        for (int kk2 = 0; kk2 < 2; kk2++) {
            short8 af[2], bf[2];
#pragma unroll
            for (int i = 0; i < 2; i++)
                af[i] = *(const short8*)&Ts[(wm * 32 + i * 16 + l15) * LDH + kk2 * 32 + q8];
#pragma unroll
            for (int j = 0; j < 2; j++)
                bf[j] = *(const short8*)&Bs[0][(wn * 32 + j * 16 + l15) * LDB2 + kk2 * 32 + q8];
#pragma unroll
            for (int i = 0; i < 2; i++)
#pragma unroll
                for (int j = 0; j < 2; j++)
                    acc2[i][j] = __builtin_amdgcn_mfma_f32_16x16x32_bf16(af[i], bf[j], acc2[i][j], 0, 0, 0);
        }
        ebar();

        // P(F2b): read Bs1 + Ts(k 64..127); stage F1a[nb+1]->Bs0; prefetch F2a[nb+1]
        if (nb < 3) {
            STAGEB(0, pX0, pX1);
            LOADB(pX0, pX1, W2t + (size_t)br * 512 + (nb + 1) * 128 + bc);
        }
#pragma unroll
        for (int kk2 = 0; kk2 < 2; kk2++) {
            short8 af[2], bf[2];
#pragma unroll
            for (int i = 0; i < 2; i++)
                af[i] = *(const short8*)&Ts[(wm * 32 + i * 16 + l15) * LDH + 64 + kk2 * 32 + q8];
#pragma unroll
            for (int j = 0; j < 2; j++)
                bf[j] = *(const short8*)&Bs[1][(wn * 32 + j * 16 + l15) * LDB2 + kk2 * 32 + q8];
#pragma unroll
            for (int i = 0; i < 2; i++)
#pragma unroll
                for (int j = 0; j < 2; j++)
                    acc2[i][j] = __builtin_amdgcn_mfma_f32_16x16x32_bf16(af[i], bf[j], acc2[i][j], 0, 0, 0);
        }
        ebar();
    }

    // ---- LN2: out = LN(acc2 + b2 + h) (f32) ----
    {
        float b2v[2], gv[2], bv[2];
#pragma unroll
        for (int j = 0; j < 2; j++) {
            const int gn = wn * 32 + j * 16 + l15;
            b2v[j] = b2[gn]; gv[j] = g2[gn]; bv[j] = b2ln[gn];
        }
#pragma unroll
        for (int i = 0; i < 2; i++) {
#pragma unroll
            for (int r = 0; r < 4; r++) {
                const int row = wm * 32 + i * 16 + rq + r;
                float s = 0.f, ss = 0.f;
#pragma unroll
                for (int j = 0; j < 2; j++) {
                    const int gn = wn * 32 + j * 16 + l15;
                    float v = acc2[i][j][r] + b2v[j] + b2f(Hs[row * LDH + gn]);
                    acc2[i][j][r] = v;
                    s += v; ss += v * v;
                }
                s  += __shfl_xor(s, 1);  s  += __shfl_xor(s, 2);  s  += __shfl_xor(s, 4);  s  += __shfl_xor(s, 8);
                ss += __shfl_xor(ss, 1); ss += __shfl_xor(ss, 2); ss += __shfl_xor(ss, 4); ss += __shfl_xor(ss, 8);
                if (l15 == 0) { red[0][wn][row] = s; red[1][wn][row] = ss; }
            }
        }
        ebar();
#pragma unroll
        for (int i = 0; i < 2; i++) {
#pragma unroll
            for (int r = 0; r < 4; r++) {
                const int row = wm * 32 + i * 16 + rq + r;
                const int gm = mBase + row;
                if (gm >= N_NODESC) continue;
                const float s  = red[0][0][row] + red[0][1][row] + red[0][2][row] + red[0][3][row];
                const float ss = red[1][0][row] + red[1][1][row] + red[1][2][row] + red[1][3][row];
                const float mean = s * (1.f / 128.f);
                const float var  = ss * (1.f / 128.f) - mean * mean;
                const float rstd = rsqrtf(var + 1e-5f);
#pragma unroll
                for (int j = 0; j < 2; j++) {
                    const int gn = wn * 32 + j * 16 + l15;
                    out[(size_t)gm * DD + gn] = (acc2[i][j][r] - mean) * rstd * gv[j] + bv[j];
                }
            }
        }
    }
}

extern "C" void kernel_launch(void* const* d_in, const int* in_sizes, int n_in,
                              void* d_out, int out_size, void* d_ws, size_t ws_size,
                              hipStream_t stream)
{
    const float* x     = (const float*)d_in[0];
    const int*   ei    = (const int*)d_in[1];
    const int*   etyp  = (const int*)d_in[2];
    const int*   ntype = (const int*)d_in[3];
    const float* Wq    = (const float*)d_in[4];
    const float* Wk    = (const float*)d_in[5];
    const float* Wv    = (const float*)d_in[6];
    const float* We    = (const float*)d_in[7];
    const float* mu    = (const float*)d_in[8];
    const float* Wout  = (const float*)d_in[9];
    const float* bout  = (const float*)d_in[10];
    const float* g1    = (const float*)d_in[11];
    const float* b1ln  = (const float*)d_in[12];
    const float* W1    = (const float*)d_in[13];
    const float* b1    = (const float*)d_in[14];
    const float* W2    = (const float*)d_in[15];
    const float* b2    = (const float*)d_in[16];
    const float* g2    = (const float*)d_in[17];
    const float* b2ln  = (const float*)d_in[18];
    float* out = (float*)d_out;

    char* ws = (char*)d_ws;
    ushort*        KV8   = (ushort*)(ws + KV8_OFF);
    unsigned char* Qt8   = (unsigned char*)(ws + QT8_OFF);
    ushort*        Xp    = (ushort*)(ws + XP_OFF);
    ushort*        agg   = (ushort*)(ws + AGG_OFF);
    ushort*        Woutt = (ushort*)(ws + WOUTT_OFF);
    ushort*        W1t   = (ushort*)(ws + W1T_OFF);
    ushort*        W2t   = (ushort*)(ws + W2T_OFF);
    ushort*        Whpf  = (ushort*)(ws + WHPF_OFF);
    int*           edata = (int*)(ws + EDATA_OFF);
    int*           rows  = (int*)(ws + ROWS_OFF);
    int*           origof= (int*)(ws + ORIG_OFF);
    int*           deg   = (int*)(ws + DEG_OFF);
    int*           tofs  = (int*)(ws + TOFS_OFF);
    int*           bh    = (int*)(ws + BH_OFF);
    int*           bb    = (int*)(ws + BB_OFF);
    unsigned int*  tmp   = (unsigned int*)(ws + TMP_OFF);
    int*           rloc  = (int*)(ws + RLOC_OFF);
    int*           csum  = (int*)(ws + CSUM_OFF);

    const int* srcA = ei;
    const int* dstA = ei + N_EDGESC;

    (void)hipMemsetAsync(ws + DEG_OFF, 0, 200000, stream);

    // A: weights | type hist | deg+rank  (independent ranges, one dispatch)
    prep_a<<<WPB + NPB + NEB, 256, 0, stream>>>(
        Wout, W1, W2, Wq, Wk, Wv, We, mu, Woutt, W1t, W2t, Whpf,
        ntype, bh, dstA, deg, tmp);
    // B: perm scan | wide chunk-local deg scans
    prep_b<<<1 + NPB, 256, 0, stream>>>(bh, deg, bb, tofs, rloc, csum);
    // C: scatter+Xp+rows | fill edata
    prep_c<<<NPB + NFB, 256, 0, stream>>>(ntype, x, srcA, etyp, bb, rloc, csum, tmp,
                                          origof, Xp, rows, edata);

    // head-pair K=32 projection (4x fewer MFMA than dense 128-K form)
    proj_gemm<<<dim3(782, 3), 256, 0, stream>>>(Xp, Whpf, tofs, origof,
                                                (unsigned char*)KV8, Qt8);
    edgeagg_kernel<<<N_NODESC / 2, 128, 0, stream>>>(rows, edata, Qt8,
                                                     (const unsigned char*)KV8, agg);

    // fused LN1-GEMM + FFN1 + FFN2 + LN2 (8 waves, dbuf half-panels, fast erf)
    fused_tail<<<782, 512, 0, stream>>>(agg, Woutt, W1t, W2t, x,
                                        bout, g1, b1ln, b1, b2, g2, b2ln, out);
}

// Round 9
// 309.349 us; speedup vs baseline: 1.0651x; 1.0031x over previous
//
#include <hip/hip_runtime.h>
#include <hip/hip_bf16.h>

#define N_NODESC 50000
#define N_EDGESC 800000
#define DD 128
#define HH 8
#define HDIM 16
#define N_NT 3
#define N_ET 5
#define NPB 196    // node chunks (196*256 = 50176 >= 50000)
#define NEB 400    // edge-pass blocks in kernel A
#define NFB 512    // fill blocks in kernel C
#define WPB 912    // weight-prep blocks (233472 els / 256)

// ---------------- workspace layout (bytes) ----------------
#define KV8_OFF    ((size_t)0)           // fp8 [N][256] bytes: K plane [0..127], V plane [128..255] (orig ids)
#define QT8_OFF    ((size_t)12800000)    // fp8 [N][640] 32 MB (orig ids, dead after edgeagg)
#define AGG_OFF    ((size_t)57600000)    // bf16 [N][128] 12.8 MB
#define WOUTT_OFF  ((size_t)83200000)    // bf16 [128][128] 32 KB
#define W1T_OFF    ((size_t)83232768)    // bf16 [512][128] 128 KB
#define W2T_OFF    ((size_t)83363840)    // bf16 [128][512] 128 KB
#define WHPF_OFF   ((size_t)83494912)    // bf16 [3][28672] frag-order head-pair weights, 172 KB
#define EDATA_OFF  ((size_t)84183040)    // int [E] packed src|et<<16 (orig ids), 3.2 MB
#define ROWS_OFF   ((size_t)87383040)    // int [N+1] (+pad)
#define ORIG_OFF   ((size_t)87583104)    // int [N]
#define DEG_OFF    ((size_t)87783104)    // int [N] (memset 0)
#define TOFS_OFF   ((size_t)87983104)    // int [4]
#define BH_OFF     ((size_t)87983168)    // int [3*NPB]
#define BB_OFF     ((size_t)87985536)    // int [3*NPB]
#define TMP_OFF    ((size_t)87988928)    // uint [E] packed rank<<16|nd, 3.2 MB
#define RLOC_OFF   ((size_t)91188928)    // int [N+1] chunk-local exclusive deg scan
#define CSUM_OFF   ((size_t)91389056)    // int [NPB] per-chunk deg sums

using short8 = __attribute__((ext_vector_type(8))) short;
using f32x4  = __attribute__((ext_vector_type(4))) float;
using f32x2  = __attribute__((ext_vector_type(2))) float;

__device__ __forceinline__ ushort f2b(float f) {
    __hip_bfloat16 h = __float2bfloat16(f);
    return *(ushort*)&h;
}
__device__ __forceinline__ float b2f(ushort u) {
    __hip_bfloat16 h = *(__hip_bfloat16*)&u;
    return __bfloat162float(h);
}
__device__ __forceinline__ f32x2 pk0(unsigned int w) {
    return __builtin_amdgcn_cvt_pk_f32_fp8((int)w, false);   // bytes 0,1
}
__device__ __forceinline__ f32x2 pk1(unsigned int w) {
    return __builtin_amdgcn_cvt_pk_f32_fp8((int)w, true);    // bytes 2,3
}
// exact-form gelu with A&S 7.1.26 erf approx (|err_erf| < 1.6e-7, far below bf16 lsb)
__device__ __forceinline__ float gelu_f(float v) {
    const float x = v * 0.70710678118654752f;
    const float ax = fabsf(x);
    const float d = fmaf(0.3275911f, ax, 1.0f);
    float t;
    asm("v_rcp_f32 %0, %1" : "=v"(t) : "v"(d));
    float p = fmaf(1.061405429f, t, -1.453152027f);
    p = fmaf(p, t, 1.421413741f);
    p = fmaf(p, t, -0.284496736f);
    p = fmaf(p, t, 0.254829592f);
    p = p * t;
    const float e = __expf(-ax * ax);
    const float er = 1.0f - p * e;
    const float erfx = (x < 0.f) ? -er : er;
    return 0.5f * v * (1.0f + erfx);
}
// raw barrier: waits only LDS (lgkmcnt), NOT vmcnt -- in-flight global prefetch survives.
__device__ __forceinline__ void ebar() {
    __builtin_amdgcn_sched_barrier(0);
    asm volatile("s_waitcnt lgkmcnt(0)" ::: "memory");
    __builtin_amdgcn_sched_barrier(0);
    __builtin_amdgcn_s_barrier();
    __builtin_amdgcn_sched_barrier(0);
}

// ================= kernel A: wprep (b<WPB) | phist | deg+rank (rest) =================
__global__ __launch_bounds__(256) void prep_a(
    const float* __restrict__ Wout, const float* __restrict__ W1, const float* __restrict__ W2,
    const float* __restrict__ WQ, const float* __restrict__ Wk, const float* __restrict__ Wv,
    const float* __restrict__ We, const float* __restrict__ mu,
    ushort* __restrict__ Woutt, ushort* __restrict__ W1t, ushort* __restrict__ W2t,
    ushort* __restrict__ Whpf,
    const int* __restrict__ ntype, int* __restrict__ bh,
    const int* __restrict__ dst, int* __restrict__ deg, unsigned int* __restrict__ tmp)
{
    const int b = blockIdx.x, tid = threadIdx.x;
    if (b < WPB) {
        const int gid = b * 256 + tid;
        if (gid < 16384) {                       // Woutt[n][k] = Wout[k][n]
            const int nn = gid >> 7, k = gid & 127;
            Woutt[gid] = f2b(Wout[k * 128 + nn]);
        } else if (gid < 81920) {                // W1t[n][k] = W1[k][n]
            const int i = gid - 16384;
            const int nn = i >> 7, k = i & 127;
            W1t[i] = f2b(W1[k * 512 + nn]);
        } else if (gid < 147456) {               // W2t[n][k] = W2[k][n]
            const int i = gid - 81920;
            const int nn = i >> 9, k = i & 511;
            W2t[i] = f2b(W2[k * 128 + nn]);
        } else {
            // Whpf: MFMA B-fragment-order head-pair weights.
            // [t][p(4)][j(14)][lane(64)][i(8)]: col c=j*16+(lane&15) in pair-local 224
            // (head 2p if c<112 else 2p+1), k=(lane>>4)*8+i in pair's 32 input dims.
            // Zero when k's head half != col's head (block-diagonal).
            const int idx = gid - 147456;        // < 86016
            const int t = idx / 28672;
            const int r = idx % 28672;
            const int i = r & 7;
            const int l = (r >> 3) & 63;
            const int f = r >> 9;                // 0..55
            const int j = f % 14, p = f / 14;
            const int c = j * 16 + (l & 15);     // 0..223
            const int k = ((l >> 4) << 3) + i;   // 0..31
            const int hi = (c >= 112) ? 1 : 0;
            const int h = 2 * p + hi;
            float v = 0.f;
            if ((k >> 4) == hi) {
                const int kp = k & 15;
                const int cl = c - hi * 112;     // 0..111
                if (cl < 16) {
                    v = 4.f * Wk[((t * HH + h) * HDIM + kp) * HDIM + cl];
                } else if (cl < 32) {
                    v = 4.f * Wv[((t * HH + h) * HDIM + kp) * HDIM + (cl - 16)];
                } else {
                    const int et = (cl - 32) >> 4, jj = (cl - 32) & 15;
                    const float* wq = WQ + ((t * HH + h) * HDIM + kp) * HDIM;
                    const float* we = We + ((et * HH + h) * HDIM + jj) * HDIM;
                    float s = 0.f;
#pragma unroll
                    for (int ff = 0; ff < 16; ff++) s = fmaf(wq[ff], we[ff], s);
                    v = 64.f * mu[h * N_ET + et] * s;   // 64 = 256 fp8 scale * 0.25
                }
            }
            Whpf[idx] = f2b(v);
        }
    } else if (b < WPB + NPB) {
        const int bc = b - WPB;
        const int wave = tid >> 6, lane = tid & 63;
        const int n = bc * 256 + tid;
        const int t = (n < N_NODESC) ? ntype[n] : -1;
        const unsigned long long m0 = __ballot(t == 0);
        const unsigned long long m1 = __ballot(t == 1);
        const unsigned long long m2 = __ballot(t == 2);
        __shared__ int wcnt[4][3];
        if (lane == 0) {
            wcnt[wave][0] = (int)__popcll(m0);
            wcnt[wave][1] = (int)__popcll(m1);
            wcnt[wave][2] = (int)__popcll(m2);
        }
        __syncthreads();
        if (tid < 3)
            bh[tid * NPB + bc] = wcnt[0][tid] + wcnt[1][tid] + wcnt[2][tid] + wcnt[3][tid];
    } else {
        for (int e = (b - WPB - NPB) * 256 + tid; e < N_EDGESC; e += NEB * 256) {
            const int nd = dst[e];
            const unsigned int p = (unsigned int)atomicAdd(&deg[nd], 1);
            tmp[e] = (p << 16) | (unsigned int)nd;
        }
    }
}

// ================= kernel B: permscan (block 0) | WIDE chunk-local deg scans (1..196) ============
__global__ __launch_bounds__(256) void prep_b(
    const int* __restrict__ bh, const int* __restrict__ deg,
    int* __restrict__ bb, int* __restrict__ tofs,
    int* __restrict__ rloc, int* __restrict__ csum)
{
    __shared__ int part[256];
    const int tid = threadIdx.x;
    if (blockIdx.x == 0) {
        // exclusive scan of 3*NPB=588 entries: 3 per thread
        const int base3 = tid * 3;
        int e0 = (base3 + 0 < 588) ? bh[base3 + 0] : 0;
        int e1 = (base3 + 1 < 588) ? bh[base3 + 1] : 0;
        int e2 = (base3 + 2 < 588) ? bh[base3 + 2] : 0;
        const int l0 = e0, l1 = e0 + e1, l2 = l1 + e2;
        part[tid] = l2;
        __syncthreads();
        for (int off = 1; off < 256; off <<= 1) {
            const int u = (tid >= off) ? part[tid - off] : 0;
            __syncthreads();
            part[tid] += u;
            __syncthreads();
        }
        const int tb = part[tid] - l2;
        if (base3 + 0 < 588) bb[base3 + 0] = tb;
        if (base3 + 1 < 588) bb[base3 + 1] = tb + l0;
        if (base3 + 2 < 588) bb[base3 + 2] = tb + l1;
        __syncthreads();
        if (tid == 0) {
            tofs[0] = 0;
            tofs[1] = bb[NPB];
            tofs[2] = bb[2 * NPB];
            tofs[3] = N_NODESC;
        }
    } else {
        // chunk-local exclusive scan (coalesced): chunk c covers nodes c*256..c*256+255
        const int c = blockIdx.x - 1;
        const int n = c * 256 + tid;
        const int vdeg = (n < N_NODESC) ? deg[n] : 0;
        part[tid] = vdeg;
        __syncthreads();
        for (int off = 1; off < 256; off <<= 1) {
            const int u = (tid >= off) ? part[tid - off] : 0;
            __syncthreads();
            part[tid] += u;
            __syncthreads();
        }
        if (n <= N_NODESC) rloc[n] = part[tid] - vdeg;   // includes rloc[N]
        if (tid == 255) csum[c] = part[255];
    }
}

// ================= kernel C: pscatter+rows (b<NPB) | fill edata (rest) =================
__global__ __launch_bounds__(256) void prep_c(
    const int* __restrict__ ntype,
    const int* __restrict__ src, const int* __restrict__ etype,
    const int* __restrict__ bb, const int* __restrict__ rloc, const int* __restrict__ csum,
    const unsigned int* __restrict__ tmp,
    int* __restrict__ origof, int* __restrict__ rows,
    int* __restrict__ edata)
{
    const int b = blockIdx.x, tid = threadIdx.x;
    __shared__ int cb[256];   // exclusive chunk bases
    // every block: LDS scan of csum[196] -> exclusive bases (tiny, redundant, parallel)
    {
        const int v = (tid < NPB) ? csum[tid] : 0;
        cb[tid] = v;
        __syncthreads();
        for (int off = 1; off < 256; off <<= 1) {
            const int u = (tid >= off) ? cb[tid - off] : 0;
            __syncthreads();
            cb[tid] += u;
            __syncthreads();
        }
        const int incl = cb[tid];
        __syncthreads();
        cb[tid] = incl - v;   // exclusive
        __syncthreads();
    }

    if (b < NPB) {
        const int wave = tid >> 6, lane = tid & 63;
        const int n = b * 256 + tid;
        const int t = (n < N_NODESC) ? ntype[n] : -1;
        const unsigned long long m0 = __ballot(t == 0);
        const unsigned long long m1 = __ballot(t == 1);
        const unsigned long long m2 = __ballot(t == 2);
        __shared__ int wcnt[4][3];
        if (lane == 0) {
            wcnt[wave][0] = (int)__popcll(m0);
            wcnt[wave][1] = (int)__popcll(m1);
            wcnt[wave][2] = (int)__popcll(m2);
        }
        __syncthreads();
        if (n < N_NODESC) {
            int basew = 0;
#pragma unroll
            for (int w = 0; w < 4; w++) if (w < wave) basew += wcnt[w][t];
            const unsigned long long mt = (t == 0) ? m0 : (t == 1) ? m1 : m2;
            const unsigned long long mlt = ((unsigned long long)1 << lane) - 1;
            const int p = bb[t * NPB + b] + basew + (int)__popcll(mt & mlt);
            origof[p] = n;
        }
        // final rows for this chunk (rloc[n] + chunk base); includes rows[N] from chunk 195
        if (n <= N_NODESC) rows[n] = cb[b] + rloc[n];
    } else {
        // atomic-free fill using captured ranks; rowstart = cb[chunk] + rloc[nd]
        for (int e = (b - NPB) * 256 + tid; e < N_EDGESC; e += NFB * 256) {
            const unsigned int v = tmp[e];
            const int nd = (int)(v & 0xffffu);
            const int p = (int)(v >> 16);
            edata[cb[nd >> 8] + rloc[nd] + p] = src[e] | (etype[e] << 16);
        }
    }
}

// ================= proj v2: per-head-pair K=32 MFMA (block-diag aware) ===========
// 64 permuted rows per block; gather x rows via origof (f32->bf16 in staging, no Xp buffer);
// stage per-type frag-order weights once; each output 16x16 fragment = ONE mfma (K=32 covers
// its head-pair's input dims). Epilogue: j<7 -> head 2p, else head 2p+1; jj= 0:K 1:V 2..6:Qt.
#define LDX 132

__global__ __launch_bounds__(256) void proj_gemm(
    const float* __restrict__ x, const ushort* __restrict__ Whpf,
    const int* __restrict__ tofs, const int* __restrict__ origof,
    unsigned char* __restrict__ KV8b, unsigned char* __restrict__ Qt8)
{
    const int t = blockIdx.y;
    const int rs = tofs[t], re = tofs[t + 1];
    const int mBase = rs + blockIdx.x * 64;
    if (mBase >= re) return;

    __shared__ ushort Xs[64 * LDX];      // 16896 B
    __shared__ ushort Ws[28672];         // 57344 B (frag-order, linear copy)

    const int tid = threadIdx.x;
    const int lane = tid & 63, wave = tid >> 6;
    const int l15 = lane & 15, rq = (lane >> 4) * 4;

    // stage x tile via origof gather (f32 -> bf16): 64 rows x 16 chunks of 8 floats
#pragma unroll
    for (int it = 0; it < 4; it++) {
        const int idx = it * 256 + tid;
        const int row = idx >> 4, ch = idx & 15;
        int gm = mBase + row; if (gm >= N_NODESC) gm = N_NODESC - 1;
        const int og = origof[gm];
        const float4 v0 = *(const float4*)(x + (size_t)og * DD + ch * 8);
        const float4 v1 = *(const float4*)(x + (size_t)og * DD + ch * 8 + 4);
        ushort o[8] = {f2b(v0.x), f2b(v0.y), f2b(v0.z), f2b(v0.w),
                       f2b(v1.x), f2b(v1.y), f2b(v1.z), f2b(v1.w)};
        *(uint4*)&Xs[row * LDX + ch * 8] = *(uint4*)o;
    }
    // stage weight fragments (linear)
    const ushort* Wg = Whpf + (size_t)t * 28672;
#pragma unroll
    for (int it = 0; it < 14; it++) {
        const int idx = it * 256 + tid;
        *(uint4*)&Ws[idx * 8] = *(const uint4*)(Wg + (size_t)idx * 8);
    }
    __syncthreads();

    int ogr[4]; bool vr[4];
#pragma unroll
    for (int r = 0; r < 4; r++) {
        const int gm = mBase + wave * 16 + rq + r;
        vr[r] = (gm < re);
        ogr[r] = vr[r] ? origof[gm] : 0;
    }

    for (int p = 0; p < 4; p++) {
        const short8 af = *(const short8*)&Xs[(wave * 16 + l15) * LDX + p * 32 + (lane >> 4) * 8];
#pragma unroll
        for (int j = 0; j < 14; j++) {
            const short8 bf = *(const short8*)&Ws[((p * 14 + j) * 64 + lane) * 8];
            f32x4 c = __builtin_amdgcn_mfma_f32_16x16x32_bf16(
                af, bf, (f32x4){0.f, 0.f, 0.f, 0.f}, 0, 0, 0);
            const int hi = (j >= 7) ? 1 : 0;
            const int h = 2 * p + hi;
            const int jj = j - hi * 7;           // 0:K 1:V 2..6:Qt[et]
#pragma unroll
            for (int r = 0; r < 4; r++) {
                if (!vr[r]) continue;
                const float v = c[r];
                const unsigned char b8 =
                    (unsigned char)(__builtin_amdgcn_cvt_pk_fp8_f32(v, v, 0, false) & 0xff);
                const size_t og = (size_t)ogr[r];
                if (jj == 0)      KV8b[og * 256 + h * 16 + l15] = b8;
                else if (jj == 1) KV8b[og * 256 + 128 + h * 16 + l15] = b8;
                else              Qt8[og * 640 + (jj - 2) * 128 + h * 16 + l15] = b8;
            }
        }
    }
}

// ================= fused edge pass, per-(edge,head) lane ownership, pipelined gather ==========
__global__ __launch_bounds__(128) void edgeagg_kernel(
    const int* __restrict__ rowstart, const int* __restrict__ edata,
    const unsigned char* __restrict__ Qt8, const unsigned char* __restrict__ KV8,
    ushort* __restrict__ agg)
{
    const int w = threadIdx.x >> 6;
    const int lane = threadIdx.x & 63;
    const int n = blockIdx.x * 2 + w;
    const int slot = lane >> 3;      // 0..7 edge slot
    const int h = lane & 7;          // 0..7 head

    __shared__ uint4 qs8s[2][40];    // fp8 q row: [et 0..4][128 features], 640 B per wave
    if (lane < 40)
        qs8s[w][lane] = ((const uint4*)(Qt8 + (size_t)n * 640))[lane];
    __syncthreads();
    const uint* qbase = (const uint*)&qs8s[w][0];

    const int s0 = rowstart[n], s1 = rowstart[n + 1];
    const float qsc = 1.44269504f / 1024.f;   // log2e / 1024 (fp8 scale folding)

    float acc[16];
#pragma unroll
    for (int j = 0; j < 16; j++) acc[j] = 0.f;
    float den = 0.f;

    // 1-deep software pipeline: next iteration's edata + K/V gather issues before
    // the current iteration's ~45-VALU compute (overlaps L2/L3 gather latency).
    int i = s0 + slot;
    int ed = 0;
    uint4 kw = {0u, 0u, 0u, 0u}, vw = {0u, 0u, 0u, 0u};
    if (i < s1) {
        ed = edata[i];
        const unsigned char* kvp = KV8 + ((size_t)(ed & 0xffff) << 8);
        kw = *(const uint4*)(kvp + (h << 4));
        vw = *(const uint4*)(kvp + 128 + (h << 4));
    }
    while (i < s1) {
        const int in2 = i + 8;
        int edn = 0;
        uint4 kwn = {0u, 0u, 0u, 0u}, vwn = {0u, 0u, 0u, 0u};
        if (in2 < s1) {
            edn = edata[in2];
            const unsigned char* kvpn = KV8 + ((size_t)(edn & 0xffff) << 8);
            kwn = *(const uint4*)(kvpn + (h << 4));
            vwn = *(const uint4*)(kvpn + 128 + (h << 4));
        }

        const int et = ed >> 16;
        const uint4 qw = *(const uint4*)(qbase + (et << 5) + (h << 2));  // q fp8 x16

        const f32x2 q0 = pk0(qw.x), q1 = pk1(qw.x), q2 = pk0(qw.y), q3 = pk1(qw.y);
        const f32x2 q4 = pk0(qw.z), q5 = pk1(qw.z), q6 = pk0(qw.w), q7 = pk1(qw.w);
        const f32x2 k0 = pk0(kw.x), k1 = pk1(kw.x), k2 = pk0(kw.y), k3 = pk1(kw.y);
        const f32x2 k4 = pk0(kw.z), k5 = pk1(kw.z), k6 = pk0(kw.w), k7 = pk1(kw.w);

        float pa = q0.x * k0.x;
        float pb = q0.y * k0.y;
        float pc = q1.x * k1.x;
        float pd = q1.y * k1.y;
        pa = fmaf(q2.x, k2.x, pa); pb = fmaf(q2.y, k2.y, pb);
        pc = fmaf(q3.x, k3.x, pc); pd = fmaf(q3.y, k3.y, pd);
        pa = fmaf(q4.x, k4.x, pa); pb = fmaf(q4.y, k4.y, pb);
        pc = fmaf(q5.x, k5.x, pc); pd = fmaf(q5.y, k5.y, pd);
        pa = fmaf(q6.x, k6.x, pa); pb = fmaf(q6.y, k6.y, pb);
        pc = fmaf(q7.x, k7.x, pc); pd = fmaf(q7.y, k7.y, pd);

        const float ex = exp2f(((pa + pb) + (pc + pd)) * qsc);
        den += ex;

        const f32x2 v0 = pk0(vw.x), v1 = pk1(vw.x), v2 = pk0(vw.y), v3 = pk1(vw.y);
        const f32x2 v4 = pk0(vw.z), v5 = pk1(vw.z), v6 = pk0(vw.w), v7 = pk1(vw.w);
        acc[0]  = fmaf(ex, v0.x, acc[0]);  acc[1]  = fmaf(ex, v0.y, acc[1]);
        acc[2]  = fmaf(ex, v1.x, acc[2]);  acc[3]  = fmaf(ex, v1.y, acc[3]);
        acc[4]  = fmaf(ex, v2.x, acc[4]);  acc[5]  = fmaf(ex, v2.y, acc[5]);
        acc[6]  = fmaf(ex, v3.x, acc[6]);  acc[7]  = fmaf(ex, v3.y, acc[7]);
        acc[8]  = fmaf(ex, v4.x, acc[8]);  acc[9]  = fmaf(ex, v4.y, acc[9]);
        acc[10] = fmaf(ex, v5.x, acc[10]); acc[11] = fmaf(ex, v5.y, acc[11]);
        acc[12] = fmaf(ex, v6.x, acc[12]); acc[13] = fmaf(ex, v6.y, acc[13]);
        acc[14] = fmaf(ex, v7.x, acc[14]); acc[15] = fmaf(ex, v7.y, acc[15]);

        i = in2; ed = edn; kw = kwn; vw = vwn;
    }

    // halving-exchange reduce over the 8 slots sharing head h (lane bits 3,4,5).
    {
        const int b0 = slot & 1, b1 = slot & 2, b2 = slot & 4;
#pragma unroll
        for (int j = 0; j < 8; j++) {
            const float v = b0 ? acc[j] : acc[j + 8];
            const float r = __shfl_xor(v, 8);
            acc[j] = (b0 ? acc[j + 8] : acc[j]) + r;
        }
#pragma unroll
        for (int j = 0; j < 4; j++) {
            const float v = b1 ? acc[j] : acc[j + 4];
            const float r = __shfl_xor(v, 16);
            acc[j] = (b1 ? acc[j + 4] : acc[j]) + r;
        }
#pragma unroll
        for (int j = 0; j < 2; j++) {
            const float v = b2 ? acc[j] : acc[j + 2];
            const float r = __shfl_xor(v, 32);
            acc[j] = (b2 ? acc[j + 2] : acc[j]) + r;
        }
        den += __shfl_xor(den, 8);
        den += __shfl_xor(den, 16);
        den += __shfl_xor(den, 32);
    }
    const float rr = 0.25f / (den + 1e-10f);   // undo V x4 scale
    const int fb = (h << 4) + ((slot & 1) << 3) + ((slot & 2) << 1) + ((slot & 4) >> 1);
    ushort o2[2] = { f2b(acc[0] * rr), f2b(acc[1] * rr) };
    *(uint*)&agg[((size_t)n << 7) + fb] = *(uint*)o2;
}

// ================= fused tail v5: 8 waves, dbuf 64-K panels, one ebar per half-phase ============
#define LDH 132
#define LDB2 68

#define LOADB(P0, P1, PTR) { P0 = *(const short8*)(PTR); P1 = *(const short8*)((PTR) + 8); }
#define STAGEB(BUF, P0, P1) { *(short8*)&Bs[BUF][br * LDB2 + bc] = P0; \
                              *(short8*)&Bs[BUF][br * LDB2 + bc + 8] = P1; }

__global__ __launch_bounds__(512, 4) void fused_tail(
    const ushort* __restrict__ agg, const ushort* __restrict__ Woutt,
    const ushort* __restrict__ W1t, const ushort* __restrict__ W2t,
    const float* __restrict__ x,
    const float* __restrict__ bout, const float* __restrict__ g1, const float* __restrict__ b1ln,
    const float* __restrict__ b1, const float* __restrict__ b2,
    const float* __restrict__ g2, const float* __restrict__ b2ln,
    float* __restrict__ out)
{
    __shared__ ushort Bs[2][128 * LDB2];   // 2 x 17408 B
    __shared__ ushort Hs[64 * LDH];        // h tile (LN1 out; FFN1 A; LN2 residual)
    __shared__ ushort Ts[64 * LDH];        // GEMM1 A-tile, then gelu(t) chunk (FFN2 A)
    __shared__ float red[2][4][64];

    const int tid = threadIdx.x;
    const int lane = tid & 63, wave = tid >> 6;
    const int wm = wave >> 2, wn = wave & 3;
    const int l15 = lane & 15, q8 = (lane >> 4) * 8, rq = (lane >> 4) * 4;
    const int mBase = blockIdx.x * 64;

    const int br = tid >> 2, bc = (tid & 3) * 16;   // B staging: 128 rows x 64 cols
    const int ar = tid >> 3, ac = (tid & 7) * 16;   // A staging: 64 rows x 128 cols
    int rowA = mBase + ar; if (rowA >= N_NODESC) rowA = N_NODESC - 1;

    f32x4 acc1[2][2], acc2[2][2];
#pragma unroll
    for (int i = 0; i < 2; i++)
#pragma unroll
        for (int j = 0; j < 2; j++) {
            acc1[i][j] = (f32x4){0.f, 0.f, 0.f, 0.f};
            acc2[i][j] = (f32x4){0.f, 0.f, 0.f, 0.f};
        }

    // prologue: load G1a->pX, G1b->pY, A-tile; stage A + G1a; prefetch F1a0->pX
    short8 pX0, pX1, pY0, pY1, aT0, aT1;
    LOADB(pX0, pX1, Woutt + (size_t)br * 128 + bc);
    LOADB(pY0, pY1, Woutt + (size_t)br * 128 + 64 + bc);
    aT0 = *(const short8*)(agg + (size_t)rowA * DD + ac);
    aT1 = *(const short8*)(agg + (size_t)rowA * DD + ac + 8);
    float xv[2][4][2];
#pragma unroll
    for (int i = 0; i < 2; i++)
#pragma unroll
        for (int r = 0; r < 4; r++) {
            const int gm = mBase + wm * 32 + i * 16 + rq + r;
            const int gr = (gm < N_NODESC) ? gm : N_NODESC - 1;
#pragma unroll
            for (int j = 0; j < 2; j++)
                xv[i][r][j] = x[(size_t)gr * DD + wn * 32 + j * 16 + l15];
        }
    *(short8*)&Ts[ar * LDH + ac] = aT0;
    *(short8*)&Ts[ar * LDH + ac + 8] = aT1;
    STAGEB(0, pX0, pX1);
    LOADB(pX0, pX1, W1t + (size_t)br * 128 + bc);               // F1a0
    ebar();

    // P(G1a): read Bs0 + Ts; stage G1b->Bs1; prefetch F1b0
    STAGEB(1, pY0, pY1);
    LOADB(pY0, pY1, W1t + (size_t)br * 128 + 64 + bc);          // F1b0
#pragma unroll
    for (int kk2 = 0; kk2 < 2; kk2++) {
        short8 af[2], bf[2];
#pragma unroll
        for (int i = 0; i < 2; i++)
            af[i] = *(const short8*)&Ts[(wm * 32 + i * 16 + l15) * LDH + kk2 * 32 + q8];
#pragma unroll
        for (int j = 0; j < 2; j++)
            bf[j] = *(const short8*)&Bs[0][(wn * 32 + j * 16 + l15) * LDB2 + kk2 * 32 + q8];
#pragma unroll
        for (int i = 0; i < 2; i++)
#pragma unroll
            for (int j = 0; j < 2; j++)
                acc1[i][j] = __builtin_amdgcn_mfma_f32_16x16x32_bf16(af[i], bf[j], acc1[i][j], 0, 0, 0);
    }
    ebar();

    // P(G1b): read Bs1 + Ts(k 64..127); stage F1a0->Bs0; prefetch F2a0
    STAGEB(0, pX0, pX1);
    LOADB(pX0, pX1, W2t + (size_t)br * 512 + bc);               // F2a0
#pragma unroll
    for (int kk2 = 0; kk2 < 2; kk2++) {
        short8 af[2], bf[2];
#pragma unroll
        for (int i = 0; i < 2; i++)
            af[i] = *(const short8*)&Ts[(wm * 32 + i * 16 + l15) * LDH + 64 + kk2 * 32 + q8];
#pragma unroll
        for (int j = 0; j < 2; j++)
            bf[j] = *(const short8*)&Bs[1][(wn * 32 + j * 16 + l15) * LDB2 + kk2 * 32 + q8];
#pragma unroll
        for (int i = 0; i < 2; i++)
#pragma unroll
            for (int j = 0; j < 2; j++)
                acc1[i][j] = __builtin_amdgcn_mfma_f32_16x16x32_bf16(af[i], bf[j], acc1[i][j], 0, 0, 0);
    }
    ebar();

    // ---- LN1: h = LN(acc1 + bout + x) -> Hs ----
    {
        float bo[2], gv[2], bv[2];
#pragma unroll
        for (int j = 0; j < 2; j++) {
            const int gn = wn * 32 + j * 16 + l15;
            bo[j] = bout[gn]; gv[j] = g1[gn]; bv[j] = b1ln[gn];
        }
#pragma unroll
        for (int i = 0; i < 2; i++) {
#pragma unroll
            for (int r = 0; r < 4; r++) {
                const int row = wm * 32 + i * 16 + rq + r;
                float s = 0.f, ss = 0.f;
#pragma unroll
                for (int j = 0; j < 2; j++) {
                    float v = acc1[i][j][r] + bo[j] + xv[i][r][j];
                    acc1[i][j][r] = v;
                    s += v; ss += v * v;
                }
                s  += __shfl_xor(s, 1);  s  += __shfl_xor(s, 2);  s  += __shfl_xor(s, 4);  s  += __shfl_xor(s, 8);
                ss += __shfl_xor(ss, 1); ss += __shfl_xor(ss, 2); ss += __shfl_xor(ss, 4); ss += __shfl_xor(ss, 8);
                if (l15 == 0) { red[0][wn][row] = s; red[1][wn][row] = ss; }
            }
        }
        ebar();
#pragma unroll
        for (int i = 0; i < 2; i++) {
#pragma unroll
            for (int r = 0; r < 4; r++) {
                const int row = wm * 32 + i * 16 + rq + r;
                const float s  = red[0][0][row] + red[0][1][row] + red[0][2][row] + red[0][3][row];
                const float ss = red[1][0][row] + red[1][1][row] + red[1][2][row] + red[1][3][row];
                const float mean = s * (1.f / 128.f);
                const float var  = ss * (1.f / 128.f) - mean * mean;
                const float rstd = rsqrtf(var + 1e-5f);
#pragma unroll
                for (int j = 0; j < 2; j++) {
                    const int gn = wn * 32 + j * 16 + l15;
                    Hs[row * LDH + gn] = f2b((acc1[i][j][r] - mean) * rstd * gv[j] + bv[j]);
                }
            }
        }
        ebar();   // publish Hs
    }

    // ---- FFN loop: per nb {F1a, F1b, gelu->Ts, F2a, F2b} ----
    for (int nb = 0; nb < 4; nb++) {
        f32x4 a1[2][2];
#pragma unroll
        for (int i = 0; i < 2; i++)
#pragma unroll
            for (int j = 0; j < 2; j++) a1[i][j] = (f32x4){0.f, 0.f, 0.f, 0.f};

        // P(F1a): read Bs0 + Hs(k 0..63); stage F1b->Bs1; prefetch F2b[nb]
        STAGEB(1, pY0, pY1);
        LOADB(pY0, pY1, W2t + (size_t)br * 512 + nb * 128 + 64 + bc);
#pragma unroll
        for (int kk2 = 0; kk2 < 2; kk2++) {
            short8 af[2], bf[2];
#pragma unroll
            for (int i = 0; i < 2; i++)
                af[i] = *(const short8*)&Hs[(wm * 32 + i * 16 + l15) * LDH + kk2 * 32 + q8];
#pragma unroll
            for (int j = 0; j < 2; j++)
                bf[j] = *(const short8*)&Bs[0][(wn * 32 + j * 16 + l15) * LDB2 + kk2 * 32 + q8];
#pragma unroll
            for (int i = 0; i < 2; i++)
#pragma unroll
                for (int j = 0; j < 2; j++)
                    a1[i][j] = __builtin_amdgcn_mfma_f32_16x16x32_bf16(af[i], bf[j], a1[i][j], 0, 0, 0);
        }
        ebar();

        // P(F1b): read Bs1 + Hs(k 64..127); stage F2a->Bs0; prefetch F1a[nb+1]
        STAGEB(0, pX0, pX1);
        if (nb < 3) { LOADB(pX0, pX1, W1t + (size_t)((nb + 1) * 128 + br) * 128 + bc); }
#pragma unroll
        for (int kk2 = 0; kk2 < 2; kk2++) {
            short8 af[2], bf[2];
#pragma unroll
            for (int i = 0; i < 2; i++)
                af[i] = *(const short8*)&Hs[(wm * 32 + i * 16 + l15) * LDH + 64 + kk2 * 32 + q8];
#pragma unroll
            for (int j = 0; j < 2; j++)
                bf[j] = *(const short8*)&Bs[1][(wn * 32 + j * 16 + l15) * LDB2 + kk2 * 32 + q8];
#pragma unroll
            for (int i = 0; i < 2; i++)
#pragma unroll
                for (int j = 0; j < 2; j++)
                    a1[i][j] = __builtin_amdgcn_mfma_f32_16x16x32_bf16(af[i], bf[j], a1[i][j], 0, 0, 0);
        }
        ebar();

        // gelu -> Ts
        {
            float b1v[2];
#pragma unroll
            for (int j = 0; j < 2; j++)
                b1v[j] = b1[nb * 128 + wn * 32 + j * 16 + l15];
#pragma unroll
            for (int i = 0; i < 2; i++)
#pragma unroll
                for (int j = 0; j < 2; j++)
#pragma unroll
                    for (int r = 0; r < 4; r++) {
                        const int row = wm * 32 + i * 16 + rq + r;
                        const int col = wn * 32 + j * 16 + l15;
                        Ts[row * LDH + col] = f2b(gelu_f(a1[i][j][r] + b1v[j]));
                    }
        }
        ebar();   // publish Ts

        // P(F2a): read Bs0 + Ts(k 0..63); stage F2b->Bs1; prefetch F1b[nb+1]
        STAGEB(1, pY0, pY1);
        if (nb < 3) { LOADB(pY0, pY1, W1t + (size_t)((nb + 1) * 128 + br) * 128 + 64 + bc); }
#pragma unroll
        for (int kk2 = 0; kk2 < 2; kk2++) {
            short8 af[2], bf[2];
#pragma unroll
            for (int i = 0; i < 2; i++)
                af[i] = *(const short8*)&Ts[(wm * 32 + i * 16 + l15) * LDH + kk2 * 32 + q8];
#pragma unroll
            for (int j = 0; j < 2; j++)
                bf[j] = *(const short8*)&Bs[0][(wn * 32 + j * 16 + l15) * LDB2 + kk2 * 32 + q8];
#pragma unroll
            for (int i = 0; i < 2; i++)
#pragma unroll
                for (int j = 0; j < 2; j++)
                    acc2[i][j] = __builtin_amdgcn_mfma_f32_16x16x32_bf16(af[i], bf[j], acc2[i][j], 0, 0, 0);
        }
        ebar();

        // P(F2b): read Bs1 + Ts(k 64..127); stage F1a[nb+1]->Bs0; prefetch F2a[nb+1]
        if (nb < 3) {
            STAGEB(0, pX0, pX1);
            LOADB(pX0, pX1, W2t + (size_t)br * 512 + (nb + 1) * 128 + bc);
        }
#pragma unroll
        for (int kk2 = 0; kk2 < 2; kk2++) {
            short8 af[2], bf[2];
#pragma unroll
            for (int i = 0; i < 2; i++)
                af[i] = *(const short8*)&Ts[(wm * 32 + i * 16 + l15) * LDH + 64 + kk2 * 32 + q8];
#pragma unroll
            for (int j = 0; j < 2; j++)
                bf[j] = *(const short8*)&Bs[1][(wn * 32 + j * 16 + l15) * LDB2 + kk2 * 32 + q8];
#pragma unroll
            for (int i = 0; i < 2; i++)
#pragma unroll
                for (int j = 0; j < 2; j++)
                    acc2[i][j] = __builtin_amdgcn_mfma_f32_16x16x32_bf16(af[i], bf[j], acc2[i][j], 0, 0, 0);
        }
        ebar();
    }

    // ---- LN2: out = LN(acc2 + b2 + h) (f32) ----
    {
        float b2v[2], gv[2], bv[2];
#pragma unroll
        for (int j = 0; j < 2; j++) {
            const int gn = wn * 32 + j * 16 + l15;
            b2v[j] = b2[gn]; gv[j] = g2[gn]; bv[j] = b2ln[gn];
        }
#pragma unroll
        for (int i = 0; i < 2; i++) {
#pragma unroll
            for (int r = 0; r < 4; r++) {
                const int row = wm * 32 + i * 16 + rq + r;
                float s = 0.f, ss = 0.f;
#pragma unroll
                for (int j = 0; j < 2; j++) {
                    const int gn = wn * 32 + j * 16 + l15;
                    float v = acc2[i][j][r] + b2v[j] + b2f(Hs[row * LDH + gn]);
                    acc2[i][j][r] = v;
                    s += v; ss += v * v;
                }
                s  += __shfl_xor(s, 1);  s  += __shfl_xor(s, 2);  s  += __shfl_xor(s, 4);  s  += __shfl_xor(s, 8);
                ss += __shfl_xor(ss, 1); ss += __shfl_xor(ss, 2); ss += __shfl_xor(ss, 4); ss += __shfl_xor(ss, 8);
                if (l15 == 0) { red[0][wn][row] = s; red[1][wn][row] = ss; }
            }
        }
        ebar();
#pragma unroll
        for (int i = 0; i < 2; i++) {
#pragma unroll
            for (int r = 0; r < 4; r++) {
                const int row = wm * 32 + i * 16 + rq + r;
                const int gm = mBase + row;
                if (gm >= N_NODESC) continue;
                const float s  = red[0][0][row] + red[0][1][row] + red[0][2][row] + red[0][3][row];
                const float ss = red[1][0][row] + red[1][1][row] + red[1][2][row] + red[1][3][row];
                const float mean = s * (1.f / 128.f);
                const float var  = ss * (1.f / 128.f) - mean * mean;
                const float rstd = rsqrtf(var + 1e-5f);
#pragma unroll
                for (int j = 0; j < 2; j++) {
                    const int gn = wn * 32 + j * 16 + l15;
                    out[(size_t)gm * DD + gn] = (acc2[i][j][r] - mean) * rstd * gv[j] + bv[j];
                }
            }
        }
    }
}

extern "C" void kernel_launch(void* const* d_in, const int* in_sizes, int n_in,
                              void* d_out, int out_size, void* d_ws, size_t ws_size,
                              hipStream_t stream)
{
    const float* x     = (const float*)d_in[0];
    const int*   ei    = (const int*)d_in[1];
    const int*   etyp  = (const int*)d_in[2];
    const int*   ntype = (const int*)d_in[3];
    const float* Wq    = (const float*)d_in[4];
    const float* Wk    = (const float*)d_in[5];
    const float* Wv    = (const float*)d_in[6];
    const float* We    = (const float*)d_in[7];
    const float* mu    = (const float*)d_in[8];
    const float* Wout  = (const float*)d_in[9];
    const float* bout  = (const float*)d_in[10];
    const float* g1    = (const float*)d_in[11];
    const float* b1ln  = (const float*)d_in[12];
    const float* W1    = (const float*)d_in[13];
    const float* b1    = (const float*)d_in[14];
    const float* W2    = (const float*)d_in[15];
    const float* b2    = (const float*)d_in[16];
    const float* g2    = (const float*)d_in[17];
    const float* b2ln  = (const float*)d_in[18];
    float* out = (float*)d_out;

    char* ws = (char*)d_ws;
    ushort*        KV8   = (ushort*)(ws + KV8_OFF);
    unsigned char* Qt8   = (unsigned char*)(ws + QT8_OFF);
    ushort*        agg   = (ushort*)(ws + AGG_OFF);
    ushort*        Woutt = (ushort*)(ws + WOUTT_OFF);
    ushort*        W1t   = (ushort*)(ws + W1T_OFF);
    ushort*        W2t   = (ushort*)(ws + W2T_OFF);
    ushort*        Whpf  = (ushort*)(ws + WHPF_OFF);
    int*           edata = (int*)(ws + EDATA_OFF);
    int*           rows  = (int*)(ws + ROWS_OFF);
    int*           origof= (int*)(ws + ORIG_OFF);
    int*           deg   = (int*)(ws + DEG_OFF);
    int*           tofs  = (int*)(ws + TOFS_OFF);
    int*           bh    = (int*)(ws + BH_OFF);
    int*           bb    = (int*)(ws + BB_OFF);
    unsigned int*  tmp   = (unsigned int*)(ws + TMP_OFF);
    int*           rloc  = (int*)(ws + RLOC_OFF);
    int*           csum  = (int*)(ws + CSUM_OFF);

    const int* srcA = ei;
    const int* dstA = ei + N_EDGESC;

    (void)hipMemsetAsync(ws + DEG_OFF, 0, 200000, stream);

    // A: weights | type hist | deg+rank  (independent ranges, one dispatch)
    prep_a<<<WPB + NPB + NEB, 256, 0, stream>>>(
        Wout, W1, W2, Wq, Wk, Wv, We, mu, Woutt, W1t, W2t, Whpf,
        ntype, bh, dstA, deg, tmp);
    // B: perm scan | wide chunk-local deg scans
    prep_b<<<1 + NPB, 256, 0, stream>>>(bh, deg, bb, tofs, rloc, csum);
    // C: scatter+rows | fill edata (no Xp copy -- proj gathers x directly)
    prep_c<<<NPB + NFB, 256, 0, stream>>>(ntype, srcA, etyp, bb, rloc, csum, tmp,
                                          origof, rows, edata);

    // head-pair K=32 projection (gathers x via origof, f32->bf16 in staging)
    proj_gemm<<<dim3(782, 3), 256, 0, stream>>>(x, Whpf, tofs, origof,
                                                (unsigned char*)KV8, Qt8);
    edgeagg_kernel<<<N_NODESC / 2, 128, 0, stream>>>(rows, edata, Qt8,
                                                     (const unsigned char*)KV8, agg);

    // fused LN1-GEMM + FFN1 + FFN2 + LN2 (8 waves, dbuf half-panels, fast erf)
    fused_tail<<<782, 512, 0, stream>>>(agg, Woutt, W1t, W2t, x,
                                        bout, g1, b1ln, b1, b2, g2, b2ln, out);
}